// Round 6
// baseline (258.239 us; speedup 1.0000x reference)
//
#include <hip/hip_runtime.h>
#include <hip/hip_bf16.h>

// ---------- types ----------
typedef short bf16x8 __attribute__((ext_vector_type(8)));
typedef float f32x4  __attribute__((ext_vector_type(4)));

__device__ __forceinline__ short f2bf(float f) {
    union { float f; unsigned u; } x; x.f = f;
    unsigned r = x.u + 0x7fffu + ((x.u >> 16) & 1u);   // RTNE
    return (short)(r >> 16);
}

// round-half-up bf16 in top 16 bits (max err = half ULP, no coherent bias)
__device__ __forceinline__ unsigned rbits(float f) {
    union { float f; unsigned u; } x; x.f = f;
    return x.u + 0x8000u;
}
// pack 2 f32 -> 2 bf16 (lo=a, hi=b): one v_perm_b32 selecting top halves.
__device__ __forceinline__ int pack2(float a, float b) {
    return (int)__builtin_amdgcn_perm(rbits(b), rbits(a), 0x07060302u);
}

__device__ __forceinline__ f32x4 mfma32k(bf16x8 a, bf16x8 b, f32x4 c) {
    return __builtin_amdgcn_mfma_f32_16x16x32_bf16(a, b, c, 0, 0, 0);
}

#define GLDS16(g, l)                                                            \
    __builtin_amdgcn_global_load_lds(                                           \
        (const __attribute__((address_space(1))) void*)(g),                     \
        (__attribute__((address_space(3))) void*)(l), 16, 0, 0)

// ---------- problem constants ----------
static constexpr int Bb = 4, Ss = 2048, Ee = 1024, Hh = 16, Dd = 64;
static constexpr int Mrows = Bb * Ss;          // 8192
static constexpr float CL2 = 0.1803368801111204f;  // log2(e)/sqrt(D)

// ---------- fused fp32 -> bf16 convert (X + 4 weights; Wq pre-scaled by CL2) ----------
__global__ void cvt_all(const float* __restrict__ X,  const float* __restrict__ Wq,
                        const float* __restrict__ Wk, const float* __restrict__ Wv,
                        const float* __restrict__ Wo,
                        short* __restrict__ Xb, short* __restrict__ Wqk,
                        short* __restrict__ Wvb, short* __restrict__ Wob) {
    int bid = blockIdx.x;
    const float* src; short* dst; int off; float scale = 1.0f;
    if (bid < 8192) {                      // X: 8192 blocks
        src = X; dst = Xb; off = bid * 1024;
    } else {
        int wsel = (bid - 8192) >> 10;     // 1024 blocks per weight
        off = ((bid - 8192) & 1023) * 1024;
        if      (wsel == 0) { src = Wq; dst = Wqk;                scale = CL2; }
        else if (wsel == 1) { src = Wk; dst = Wqk + Ee * Ee; }
        else if (wsel == 2) { src = Wv; dst = Wvb; }
        else                { src = Wo; dst = Wob; }
    }
    int i = off + threadIdx.x * 4;
    float4 v = *(const float4*)(src + i);
    short4 o;
    o.x = f2bf(v.x * scale); o.y = f2bf(v.y * scale);
    o.z = f2bf(v.z * scale); o.w = f2bf(v.w * scale);
    *(short4*)(dst + i) = o;
}

// ---------- fused projection GEMMs (QK + V^T): 256x256 8-phase (R9) ----------
// blocks [0,256): C0[8192][2048] = Xb @ Wqk^T      (bm=wg&31, bn=wg>>5)
// blocks [256,384): C1[1024][8192] = Wvb @ Xb^T, kv-permuted cols (bm=v&3, bn=v>>2)
// Structure (m201 template, plain HIP): BK=64, 512 thr = 8 waves (2Mx4N), per-wave
// C = 128x64 (acc[8][4]). LDS 128KB = 2 bufs x (A 32KB + B 32KB), slot-swizzled
// (phys16Bslot = logical ^ (row&7); GLDS sources inverse-permuted, rule #21).
// R10: UNCHANGED from R9 (diagnostic round; see attn note).
__global__ __launch_bounds__(512, 2)
void gemm_fused(const short* __restrict__ A0, const short* __restrict__ B0,
                short* __restrict__ C0,
                const short* __restrict__ A1, const short* __restrict__ B1,
                short* __restrict__ C1) {
    __shared__ __align__(16) short lds[65536];   // 128 KB: [buf 32768][A 16384 | B 16384] shorts
    const int t = threadIdx.x, l = t & 63, wv = t >> 6;
    const int lane16 = l & 15, quad = l >> 4;
    const int wm = wv >> 2, wn = wv & 3;         // 2 x 4 wave grid

    // XCD-chunked bijective swizzle (384 = 8 x 48)
    int bid = blockIdx.x;
    int wg = (bid & 7) * 48 + (bid >> 3);
    const short *A, *Bm; short* C;
    int bm, bn, ldc; bool perm;
    if (wg < 256) { bm = wg & 31; bn = wg >> 5; A = A0; Bm = B0; C = C0; ldc = 2048; perm = false; }
    else { int v = wg - 256; bm = v & 3; bn = v >> 2; A = A1; Bm = B1; C = C1; ldc = 8192; perm = true; }

    const short* Ab = A  + (size_t)bm * 256 * 1024;
    const short* Bp = Bm + (size_t)bn * 256 * 1024;

    // staging: thread covers LDS slot s = half*1024 + j*512 + wv*64 + lane.
    // row = s>>3, phys_slot = lane&7; logical = phys ^ (row&7), row&7 = (t>>3)&7.
    const int grow = t >> 3;                               // 0..63
    const int lsl  = ((t & 7) ^ ((t >> 3) & 7)) * 8;       // inverse-swizzled slot (elems)
    const short* gA = Ab + (size_t)grow * 1024 + lsl;
    const short* gB = Bp + (size_t)grow * 1024 + lsl;

#define STAGE8(gsrc, matOff, half, j, T, buf)                                   \
    GLDS16((gsrc) + ((half) * 128 + (j) * 64) * 1024 + (T) * 64,                \
           lds + (buf) * 32768 + (matOff) + (half) * 8192 + (j) * 4096 + wv * 512)

    // fragment-read swizzled slots: logical slot = ks*4+quad, row&7 = lane16&7
    const int fsw0 = ((quad)     ^ (lane16 & 7)) * 8;
    const int fsw1 = ((quad + 4) ^ (lane16 & 7)) * 8;
    const int aoff = (wm * 128 + lane16) * 64;
    const int boff = (wn * 64  + lane16) * 64;

    f32x4 acc[8][4] = {};

    // ---- prologue: tile0 (all 4 halves) + tile1 A-lo; vmcnt(2) keeps 2 in flight
    STAGE8(gA, 0,     0, 0, 0, 0); STAGE8(gA, 0,     0, 1, 0, 0);
    STAGE8(gA, 0,     1, 0, 0, 0); STAGE8(gA, 0,     1, 1, 0, 0);
    STAGE8(gB, 16384, 0, 0, 0, 0); STAGE8(gB, 16384, 0, 1, 0, 0);
    STAGE8(gB, 16384, 1, 0, 0, 0); STAGE8(gB, 16384, 1, 1, 0, 0);
    STAGE8(gA, 0,     0, 0, 1, 1); STAGE8(gA, 0,     0, 1, 1, 1);
    asm volatile("s_waitcnt vmcnt(2)" ::: "memory");
    __builtin_amdgcn_s_barrier();

#define ARD(MI0)                                                                \
    a0 = *(const bf16x8*)(sAc + aoff + (MI0) * 1024 + fsw0);                    \
    a1 = *(const bf16x8*)(sAc + aoff + (MI0) * 1024 + fsw1);                    \
    a2 = *(const bf16x8*)(sAc + aoff + ((MI0) + 1) * 1024 + fsw0);              \
    a3 = *(const bf16x8*)(sAc + aoff + ((MI0) + 1) * 1024 + fsw1);

#define MFQ(MI0)                                                                \
    __builtin_amdgcn_s_setprio(1);                                              \
    _Pragma("unroll")                                                           \
    for (int nj = 0; nj < 4; ++nj) {                                            \
        acc[MI0][nj]       = mfma32k(a0, bf[nj][0], acc[MI0][nj]);              \
        acc[MI0][nj]       = mfma32k(a1, bf[nj][1], acc[MI0][nj]);              \
        acc[(MI0) + 1][nj] = mfma32k(a2, bf[nj][0], acc[(MI0) + 1][nj]);        \
        acc[(MI0) + 1][nj] = mfma32k(a3, bf[nj][1], acc[(MI0) + 1][nj]);        \
    }                                                                           \
    __builtin_amdgcn_s_setprio(0);

    for (int T = 0; T < 16; ++T) {
        const int cur = T & 1, nxt = cur ^ 1;
        const short* sAc = lds + cur * 32768;
        const short* sBc = sAc + 16384;
        bf16x8 bf[4][2];
#pragma unroll
        for (int nj = 0; nj < 4; ++nj) {
            bf[nj][0] = *(const bf16x8*)(sBc + boff + nj * 1024 + fsw0);
            bf[nj][1] = *(const bf16x8*)(sBc + boff + nj * 1024 + fsw1);
        }
        bf16x8 a0, a1, a2, a3;
        // ---- phase 0: mi {0,1}; stage A-hi(T+1) -> nxt ----
        ARD(0)
        if (T < 15) { STAGE8(gA, 0, 1, 0, T + 1, nxt); STAGE8(gA, 0, 1, 1, T + 1, nxt); }
        __builtin_amdgcn_s_barrier();
        MFQ(0)
        __builtin_amdgcn_s_barrier();
        // ---- phase 1: mi {2,3}; stage B-lo(T+1) ----
        ARD(2)
        if (T < 15) { STAGE8(gB, 16384, 0, 0, T + 1, nxt); STAGE8(gB, 16384, 0, 1, T + 1, nxt); }
        __builtin_amdgcn_s_barrier();
        MFQ(2)
        __builtin_amdgcn_s_barrier();
        // ---- phase 2: mi {4,5}; stage B-hi(T+1) ----
        ARD(4)
        if (T < 15) { STAGE8(gB, 16384, 1, 0, T + 1, nxt); STAGE8(gB, 16384, 1, 1, T + 1, nxt); }
        __builtin_amdgcn_s_barrier();
        MFQ(4)
        __builtin_amdgcn_s_barrier();
        // ---- phase 3: mi {6,7}; no stage ----
        ARD(6)
        __builtin_amdgcn_s_barrier();
        MFQ(6)
        __builtin_amdgcn_s_barrier();
        // ---- boundary: pre-issue A-lo(T+2) into cur (now free), counted wait ----
        if (T < 14) {
            STAGE8(gA, 0, 0, 0, T + 2, cur); STAGE8(gA, 0, 0, 1, T + 2, cur);
            asm volatile("s_waitcnt vmcnt(2)" ::: "memory");
            __builtin_amdgcn_s_barrier();
        } else if (T == 14) {
            asm volatile("s_waitcnt vmcnt(0)" ::: "memory");
            __builtin_amdgcn_s_barrier();
        }
    }
#undef ARD
#undef MFQ
#undef STAGE8

    // ---- epilogue ----
    const int sEven = (lane16 >> 2) * 8 + (lane16 & 3);   // kv-perm within 32-col blocks
#pragma unroll
    for (int mi = 0; mi < 8; ++mi)
#pragma unroll
        for (int nj = 0; nj < 4; ++nj) {
            int row = bm * 256 + wm * 128 + mi * 16 + quad * 4;
            int col = bn * 256 + wn * 64 + nj * 16 + lane16;
            if (perm) col = (col & ~31) | (sEven + (nj & 1) * 4);
#pragma unroll
            for (int r = 0; r < 4; ++r)
                C[(size_t)(row + r) * ldc + col] = f2bf(acc[mi][nj][r]);
        }
}

// ---------- output projection GEMM: out[M][1024] f32 = CTX @ Wo^T + bo ----------
__global__ __launch_bounds__(256, 3)
void gemm_out(const short* __restrict__ A, const short* __restrict__ Bm,
              float* __restrict__ C, const float* __restrict__ bias) {
    __shared__ __align__(16) short sA[128 * 32];
    __shared__ __align__(16) short sB[128 * 32];
    const int t = threadIdx.x, w = t >> 6, l = t & 63;
    const int lane16 = l & 15, quad = l >> 4;
    const int wm = (w >> 1) * 64, wn = (w & 1) * 64;
    const int bm = blockIdx.x, bn = blockIdx.y;

    f32x4 acc[4][4] = {};
    const short* Ab  = A  + (size_t)bm * 128 * 1024;
    const short* Bbp = Bm + (size_t)bn * 128 * 1024;
    const int s0 = w * 64 + l;
    const int ldsOff = (w * 64) * 8;

    for (int k0 = 0; k0 < 1024; k0 += 32) {
#pragma unroll
        for (int p = 0; p < 2; ++p) {
            int s = p * 256 + s0;
            int row = s >> 2, cs = s & 3;
            GLDS16(Ab + (size_t)row * 1024 + k0 + cs * 8, sA + p * 2048 + ldsOff);
            GLDS16(Bbp + (size_t)row * 1024 + k0 + cs * 8, sB + p * 2048 + ldsOff);
        }
        __syncthreads();
        bf16x8 af[4], bfr[4];
#pragma unroll
        for (int i = 0; i < 4; ++i) {
            af[i]  = *(const bf16x8*)(sA + (wm + i * 16 + lane16) * 32 + quad * 8);
            bfr[i] = *(const bf16x8*)(sB + (wn + i * 16 + lane16) * 32 + quad * 8);
        }
#pragma unroll
        for (int i = 0; i < 4; ++i)
#pragma unroll
            for (int j = 0; j < 4; ++j)
                acc[i][j] = mfma32k(af[i], bfr[j], acc[i][j]);
        __syncthreads();
    }

#pragma unroll
    for (int i = 0; i < 4; ++i)
#pragma unroll
        for (int j = 0; j < 4; ++j) {
            int row = bm * 128 + wm + i * 16 + quad * 4;
            int col = bn * 128 + wn + j * 16 + lane16;
            float bv = bias[col];
#pragma unroll
            for (int r = 0; r < 4; ++r)
                C[(size_t)(row + r) * 1024 + col] = acc[i][j][r] + bv;
        }
}

// ---------- flash attention ----------
// QK[M][2048] bf16 (Q pre-scaled by CL2 | K), VT[1024][8192] bf16 (V^T, kv-permuted
// within 32-blocks), CTX[M][1024] bf16.
// S^T = K Q^T (P^T C-layout == A-frag layout), softmax without online max
// (scores provably bounded), P packed in-register via v_perm, PV via K=32 MFMA.
// Softmax denominator accumulated on the MATRIX pipe: lacc = mfma(P, ones, lacc).
//
// R5: T2 slot-swizzle -> bank conflicts 8.45M -> 0 (verified), timing neutral.
// R6: min-2-phase prefetch -> neutral (-4%); drain was NOT critical. Reverted.
// R7: 2-deep QK(a+1)||PV(a) pipeline + setprio: 77.0 -> 75.8 (+1.5%). Kept.
// R10: DIAGNOSTIC ROUND -- attn split into two half-dispatches (bh0 = 0, 32;
//      grid (32,16) each) so the top-5 dur ranking finally surfaces the other
//      kernels (cvt/gemm_fused/gemm_out have NEVER produced a counter row; the
//      ~178us non-attn budget is unattributed). Kernel math identical; expect
//      ~5-15us residency cost this round, revert split next round.
__global__ __launch_bounds__(256, 4)
void attn_kernel(const short* __restrict__ QK, const short* __restrict__ VT,
                 short* __restrict__ CTX, int bh0) {
    // sK: [half(32d)][128 kv][32 d]   slot-swizzled
    // sV: [4 kv32-blk][64 d][32 kvp]  slot-swizzled
    __shared__ __align__(16) short sK[8192];
    __shared__ __align__(16) short sV[8192];
    const int t = threadIdx.x, w = t >> 6, l = t & 63;
    const int lane16 = l & 15, quad = l >> 4;
    const int bh = blockIdx.x + bh0, qt = blockIdx.y;
    const int b = bh >> 4, h = bh & 15;

    // swizzled slot offset for ALL fragment reads: quad ^ ((row>>1)&3); row=k*16+lane16
    const int qx8 = (quad ^ ((lane16 >> 1) & 3)) * 8;

    const short* Qb = QK + ((size_t)(b * 2048 + qt * 128)) * 2048 + h * 64;
    const short* Vb = VT + ((size_t)(h * 64)) * 8192 + (size_t)b * 2048;
    const int ldsOff = (w * 64) * 8;   // wave-uniform LDS base

    // per-lane loop-invariant staging source offsets (c = p*256 + t)
    // global slot pre-permuted by the swizzle involution: (c&3) ^ ((c>>3)&3)
    int off_kq[4], off_v[4];
#pragma unroll
    for (int p = 0; p < 4; ++p) {
        int c = p * 256 + t;
        int sw = ((c & 3) ^ ((c >> 3) & 3)) * 8;
        off_kq[p] = ((c >> 2) & 127) * 2048 + (c >> 9) * 32 + sw;
        off_v[p]  = ((c >> 2) & 63) * 8192 + (c >> 8) * 32 + sw;
    }

    // ---- stage Q into sK, read Q B-frags ----
#pragma unroll
    for (int p = 0; p < 4; ++p)
        GLDS16(Qb + off_kq[p], sK + p * 2048 + ldsOff);
    __syncthreads();
    bf16x8 qf[2][2];
#pragma unroll
    for (int mt = 0; mt < 2; ++mt)
#pragma unroll
        for (int ks = 0; ks < 2; ++ks)
            qf[mt][ks] = *(const bf16x8*)(sK + ks * 4096 + (w * 32 + mt * 16 + lane16) * 32 + qx8);
    __syncthreads();

    const short one = (short)0x3F80;   // bf16 1.0
    const bf16x8 ONE8 = {one, one, one, one, one, one, one, one};
    f32x4 lacc[2] = {};
    f32x4 o[2][4] = {};

    const short* kptr = QK + ((size_t)(b * 2048)) * 2048 + 1024 + h * 64;
    const short* vptr = Vb;

    // QK^T MFMA cluster for kv32-block a -> sc[mt][sub]
    auto QKB = [&](int a, f32x4 (&sc)[2][2]) {
        __builtin_amdgcn_s_setprio(1);
#pragma unroll
        for (int sub = 0; sub < 2; ++sub) {
            int nt = a * 2 + sub;
            bf16x8 kf0 = *(const bf16x8*)(sK + (nt * 16 + lane16) * 32 + qx8);
            bf16x8 kf1 = *(const bf16x8*)(sK + 4096 + (nt * 16 + lane16) * 32 + qx8);
#pragma unroll
            for (int mt = 0; mt < 2; ++mt) {
                f32x4 z = {};
                z = mfma32k(kf0, qf[mt][0], z);
                z = mfma32k(kf1, qf[mt][1], z);
                sc[mt][sub] = z;
            }
        }
        __builtin_amdgcn_s_setprio(0);
    };
    // exp/pack + l-accum + PV for kv32-block a (consumes sc)
    auto PVB = [&](int a, f32x4 (&sc)[2][2]) {
        bf16x8 pf[2];
#pragma unroll
        for (int mt = 0; mt < 2; ++mt) {
            union { int i[4]; bf16x8 v; } u;
#pragma unroll
            for (int sub = 0; sub < 2; ++sub) {
                f32x4 e;
#pragma unroll
                for (int r = 0; r < 4; ++r)
                    e[r] = __builtin_amdgcn_exp2f(sc[mt][sub][r]);
                u.i[sub * 2]     = pack2(e[0], e[1]);
                u.i[sub * 2 + 1] = pack2(e[2], e[3]);
            }
            pf[mt] = u.v;
        }
        __builtin_amdgcn_s_setprio(1);
#pragma unroll
        for (int mt = 0; mt < 2; ++mt)
            lacc[mt] = mfma32k(pf[mt], ONE8, lacc[mt]);
#pragma unroll
        for (int dt = 0; dt < 4; ++dt) {
            bf16x8 vf = *(const bf16x8*)(sV + a * 2048 + (dt * 16 + lane16) * 32 + qx8);
#pragma unroll
            for (int mt = 0; mt < 2; ++mt)
                o[mt][dt] = mfma32k(pf[mt], vf, o[mt][dt]);
        }
        __builtin_amdgcn_s_setprio(0);
    };

    for (int kt = 0; kt < 16; ++kt) {
        // ---- stage K tile [2][128][32] and V^T tile [4][64][32] ----
#pragma unroll
        for (int p = 0; p < 4; ++p)
            GLDS16(kptr + off_kq[p], sK + p * 2048 + ldsOff);
#pragma unroll
        for (int p = 0; p < 4; ++p)
            GLDS16(vptr + off_v[p], sV + p * 2048 + ldsOff);
        kptr += (size_t)128 * 2048;
        vptr += 128;
        __syncthreads();

        // ---- 2-deep pipeline: QK(a+1) issues before exp/PV(a) ----
        f32x4 scA[2][2], scB[2][2];
        QKB(0, scA);
        QKB(1, scB);  PVB(0, scA);
        QKB(2, scA);  PVB(1, scB);
        QKB(3, scB);  PVB(2, scA);
                      PVB(3, scB);
        __syncthreads();
    }

    // ---- epilogue: lacc rows ARE per-lane l (q = quad*4+r); ctx = O / l ----
#pragma unroll
    for (int mt = 0; mt < 2; ++mt)
#pragma unroll
        for (int r = 0; r < 4; ++r) {
            float inv = 1.0f / lacc[mt][r];
            int row = b * 2048 + qt * 128 + w * 32 + mt * 16 + quad * 4 + r;
#pragma unroll
            for (int dt = 0; dt < 4; ++dt)
                CTX[(size_t)row * 1024 + h * 64 + dt * 16 + lane16] = f2bf(o[mt][dt][r] * inv);
        }
}

// ---------- launch ----------
extern "C" void kernel_launch(void* const* d_in, const int* in_sizes, int n_in,
                              void* d_out, int out_size, void* d_ws, size_t ws_size,
                              hipStream_t stream) {
    const float* X  = (const float*)d_in[0];
    const float* Wq = (const float*)d_in[1];
    const float* Wk = (const float*)d_in[2];
    const float* Wv = (const float*)d_in[3];
    const float* Wo = (const float*)d_in[4];
    const float* bo = (const float*)d_in[5];
    float* out = (float*)d_out;

    char* ws = (char*)d_ws;
    constexpr size_t OFF_XB  = 0;                                   // 16 MB
    constexpr size_t OFF_WQK = OFF_XB  + (size_t)Mrows * Ee * 2;    //  4 MB
    constexpr size_t OFF_WV  = OFF_WQK + (size_t)2 * Ee * Ee * 2;   //  2 MB
    constexpr size_t OFF_WO  = OFF_WV  + (size_t)Ee * Ee * 2;       //  2 MB
    constexpr size_t OFF_QK  = OFF_WO  + (size_t)Ee * Ee * 2;       // 32 MB
    constexpr size_t OFF_VT  = OFF_QK  + (size_t)Mrows * 2048 * 2;  // 16 MB
    constexpr size_t OFF_CTX = OFF_VT  + (size_t)Ee * Mrows * 2;    // 16 MB
    short* Xb   = (short*)(ws + OFF_XB);
    short* Wqk  = (short*)(ws + OFF_WQK);
    short* Wvb  = (short*)(ws + OFF_WV);
    short* Wob  = (short*)(ws + OFF_WO);
    short* QKb  = (short*)(ws + OFF_QK);
    short* VTb  = (short*)(ws + OFF_VT);
    short* CTX  = (short*)(ws + OFF_CTX);

    // all converts in one launch (X, Wq*CL2 | Wk, Wv, Wo)
    cvt_all<<<12288, 256, 0, stream>>>(X, Wq, Wk, Wv, Wo, Xb, Wqk, Wvb, Wob);

    // fused 256^2 8-phase: QK projection (256 blocks) + V^T (128 blocks, kv-permuted)
    gemm_fused<<<384, 512, 0, stream>>>(Xb, Wqk, QKb, Wvb, Xb, VTb);

    // attention: CTX [8192][1024] bf16 -- split into two half-dispatches (R10 diagnostic)
    attn_kernel<<<dim3(32, Ss / 128), 256, 0, stream>>>(QKb, VTb, CTX, 0);
    attn_kernel<<<dim3(32, Ss / 128), 256, 0, stream>>>(QKb, VTb, CTX, 32);

    // output projection + bias: f32 out
    gemm_out<<<dim3(Mrows / 128, Ee / 128), 256, 0, stream>>>(CTX, Wob, out, bo);
}

// Round 7
// 248.710 us; speedup vs baseline: 1.0383x; 1.0383x over previous
//
#include <hip/hip_runtime.h>
#include <hip/hip_bf16.h>

// ---------- types ----------
typedef short bf16x8 __attribute__((ext_vector_type(8)));
typedef float f32x4  __attribute__((ext_vector_type(4)));

__device__ __forceinline__ short f2bf(float f) {
    union { float f; unsigned u; } x; x.f = f;
    unsigned r = x.u + 0x7fffu + ((x.u >> 16) & 1u);   // RTNE
    return (short)(r >> 16);
}

// round-half-up bf16 in top 16 bits (max err = half ULP, no coherent bias)
__device__ __forceinline__ unsigned rbits(float f) {
    union { float f; unsigned u; } x; x.f = f;
    return x.u + 0x8000u;
}
// pack 2 f32 -> 2 bf16 (lo=a, hi=b): one v_perm_b32 selecting top halves.
__device__ __forceinline__ int pack2(float a, float b) {
    return (int)__builtin_amdgcn_perm(rbits(b), rbits(a), 0x07060302u);
}

__device__ __forceinline__ f32x4 mfma32k(bf16x8 a, bf16x8 b, f32x4 c) {
    return __builtin_amdgcn_mfma_f32_16x16x32_bf16(a, b, c, 0, 0, 0);
}

#define GLDS16(g, l)                                                            \
    __builtin_amdgcn_global_load_lds(                                           \
        (const __attribute__((address_space(1))) void*)(g),                     \
        (__attribute__((address_space(3))) void*)(l), 16, 0, 0)

// ---------- problem constants ----------
static constexpr int Bb = 4, Ss = 2048, Ee = 1024, Hh = 16, Dd = 64;
static constexpr int Mrows = Bb * Ss;          // 8192
static constexpr float CL2 = 0.1803368801111204f;  // log2(e)/sqrt(D)

// ---------- fused fp32 -> bf16 convert (X + 4 weights; Wq pre-scaled by CL2) ----------
__global__ void cvt_all(const float* __restrict__ X,  const float* __restrict__ Wq,
                        const float* __restrict__ Wk, const float* __restrict__ Wv,
                        const float* __restrict__ Wo,
                        short* __restrict__ Xb, short* __restrict__ Wqk,
                        short* __restrict__ Wvb, short* __restrict__ Wob) {
    int bid = blockIdx.x;
    const float* src; short* dst; int off; float scale = 1.0f;
    if (bid < 8192) {                      // X: 8192 blocks
        src = X; dst = Xb; off = bid * 1024;
    } else {
        int wsel = (bid - 8192) >> 10;     // 1024 blocks per weight
        off = ((bid - 8192) & 1023) * 1024;
        if      (wsel == 0) { src = Wq; dst = Wqk;                scale = CL2; }
        else if (wsel == 1) { src = Wk; dst = Wqk + Ee * Ee; }
        else if (wsel == 2) { src = Wv; dst = Wvb; }
        else                { src = Wo; dst = Wob; }
    }
    int i = off + threadIdx.x * 4;
    float4 v = *(const float4*)(src + i);
    short4 o;
    o.x = f2bf(v.x * scale); o.y = f2bf(v.y * scale);
    o.z = f2bf(v.z * scale); o.w = f2bf(v.w * scale);
    *(short4*)(dst + i) = o;
}

// ---------- shared 256x128-tile 8-wave pipeline (R11) ----------
// Computes acc[8][2] (per-wave 128x32 of a 256x128 C-tile) over K=1024, BK=64.
// Same discipline as the R9 256^2 pipeline: double-buffered LDS (stride 32768
// shorts/buf, A@0 16384, B@16384 8192 used), slot-swizzle phys=logical^(row&7)
// on both sides, counted vmcnt(2) at the tile boundary (never 0 in steady
// state), 2 compute phases x 16 MFMA per K-tile.
// Hazard ledger: stage into a buf only after the barrier ending all reads of
// it; reads of tile T+1 sit behind boundary vmcnt(2)+barrier whose last-2
// outstanding are T+2's A-lo; prior global STORES in the vmcnt stream only
// make the wait stricter (safe). k ascending -> bit-identical accumulation.
__device__ __forceinline__ void gemm_pipe_256x128(
    short* lds, const short* hA, const short* hB,
    int wv, int lane16, int wn, int fsw0, int fsw1, int aoff,
    f32x4 (&acc)[8][2])
{
#define STG(gsrc, matOff, half, j, T, buf)                                      \
    GLDS16((gsrc) + ((half) * 128 + (j) * 64) * 1024 + (T) * 64,                \
           lds + (buf) * 32768 + (matOff) + (half) * 8192 + (j) * 4096 + wv * 512)

    // prologue: T0 A(4)+B(2); T1 A-lo(2); keep last 2 in flight
    STG(hA, 0,     0, 0, 0, 0); STG(hA, 0,     0, 1, 0, 0);
    STG(hA, 0,     1, 0, 0, 0); STG(hA, 0,     1, 1, 0, 0);
    STG(hB, 16384, 0, 0, 0, 0); STG(hB, 16384, 0, 1, 0, 0);
    STG(hA, 0,     0, 0, 1, 1); STG(hA, 0,     0, 1, 1, 1);
    asm volatile("s_waitcnt vmcnt(2)" ::: "memory");
    __builtin_amdgcn_s_barrier();

    const int bvoff = (wn * 32 + lane16) * 64;
    for (int T = 0; T < 16; ++T) {
        const int cur = T & 1, nxt = cur ^ 1;
        const short* sAc = lds + cur * 32768;
        const short* sBc = sAc + 16384;
        bf16x8 bb[2][2];
#pragma unroll
        for (int nj = 0; nj < 2; ++nj) {
            bb[nj][0] = *(const bf16x8*)(sBc + bvoff + nj * 1024 + fsw0);
            bb[nj][1] = *(const bf16x8*)(sBc + bvoff + nj * 1024 + fsw1);
        }
        bf16x8 a0, a1, a2, a3, a4, a5, a6, a7;
        // ---- phase 0: mi 0..3; stage A-hi(T+1) + B(T+1) ----
        a0 = *(const bf16x8*)(sAc + aoff + 0 * 1024 + fsw0);
        a1 = *(const bf16x8*)(sAc + aoff + 0 * 1024 + fsw1);
        a2 = *(const bf16x8*)(sAc + aoff + 1 * 1024 + fsw0);
        a3 = *(const bf16x8*)(sAc + aoff + 1 * 1024 + fsw1);
        a4 = *(const bf16x8*)(sAc + aoff + 2 * 1024 + fsw0);
        a5 = *(const bf16x8*)(sAc + aoff + 2 * 1024 + fsw1);
        a6 = *(const bf16x8*)(sAc + aoff + 3 * 1024 + fsw0);
        a7 = *(const bf16x8*)(sAc + aoff + 3 * 1024 + fsw1);
        if (T < 15) {
            STG(hA, 0,     1, 0, T + 1, nxt); STG(hA, 0,     1, 1, T + 1, nxt);
            STG(hB, 16384, 0, 0, T + 1, nxt); STG(hB, 16384, 0, 1, T + 1, nxt);
        }
        __builtin_amdgcn_s_barrier();
        __builtin_amdgcn_s_setprio(1);
#pragma unroll
        for (int nj = 0; nj < 2; ++nj) {
            acc[0][nj] = mfma32k(a0, bb[nj][0], acc[0][nj]);
            acc[0][nj] = mfma32k(a1, bb[nj][1], acc[0][nj]);
            acc[1][nj] = mfma32k(a2, bb[nj][0], acc[1][nj]);
            acc[1][nj] = mfma32k(a3, bb[nj][1], acc[1][nj]);
            acc[2][nj] = mfma32k(a4, bb[nj][0], acc[2][nj]);
            acc[2][nj] = mfma32k(a5, bb[nj][1], acc[2][nj]);
            acc[3][nj] = mfma32k(a6, bb[nj][0], acc[3][nj]);
            acc[3][nj] = mfma32k(a7, bb[nj][1], acc[3][nj]);
        }
        __builtin_amdgcn_s_setprio(0);
        __builtin_amdgcn_s_barrier();
        // ---- phase 1: mi 4..7 ----
        a0 = *(const bf16x8*)(sAc + aoff + 4 * 1024 + fsw0);
        a1 = *(const bf16x8*)(sAc + aoff + 4 * 1024 + fsw1);
        a2 = *(const bf16x8*)(sAc + aoff + 5 * 1024 + fsw0);
        a3 = *(const bf16x8*)(sAc + aoff + 5 * 1024 + fsw1);
        a4 = *(const bf16x8*)(sAc + aoff + 6 * 1024 + fsw0);
        a5 = *(const bf16x8*)(sAc + aoff + 6 * 1024 + fsw1);
        a6 = *(const bf16x8*)(sAc + aoff + 7 * 1024 + fsw0);
        a7 = *(const bf16x8*)(sAc + aoff + 7 * 1024 + fsw1);
        __builtin_amdgcn_s_barrier();
        __builtin_amdgcn_s_setprio(1);
#pragma unroll
        for (int nj = 0; nj < 2; ++nj) {
            acc[4][nj] = mfma32k(a0, bb[nj][0], acc[4][nj]);
            acc[4][nj] = mfma32k(a1, bb[nj][1], acc[4][nj]);
            acc[5][nj] = mfma32k(a2, bb[nj][0], acc[5][nj]);
            acc[5][nj] = mfma32k(a3, bb[nj][1], acc[5][nj]);
            acc[6][nj] = mfma32k(a4, bb[nj][0], acc[6][nj]);
            acc[6][nj] = mfma32k(a5, bb[nj][1], acc[6][nj]);
            acc[7][nj] = mfma32k(a6, bb[nj][0], acc[7][nj]);
            acc[7][nj] = mfma32k(a7, bb[nj][1], acc[7][nj]);
        }
        __builtin_amdgcn_s_setprio(0);
        __builtin_amdgcn_s_barrier();
        // ---- boundary: pre-issue A-lo(T+2) into cur, counted wait ----
        if (T < 14) {
            STG(hA, 0, 0, 0, T + 2, cur); STG(hA, 0, 0, 1, T + 2, cur);
            asm volatile("s_waitcnt vmcnt(2)" ::: "memory");
            __builtin_amdgcn_s_barrier();
        } else if (T == 14) {
            asm volatile("s_waitcnt vmcnt(0)" ::: "memory");
            __builtin_amdgcn_s_barrier();
        }
    }
#undef STG
}

// ---------- fused projection GEMMs: persistent 256-block grid (R11) ----------
// Each block: (phase A) one 256^2 QK tile  C0[8192][2048] = Xb @ Wqk^T
//             (phase B) one 256x128 VT half-tile C1[1024][8192] = Wvb @ Xb^T
//                       (kv-permuted within 32-col blocks, for attn PV)
// R6 counters showed the old 384-block grid ran 1.5 dispatch rounds (2nd round
// half-empty: makespan 2.0 tile-units for 1.5 of work; MfmaUtil 29.6%,
// occupancy 15%). 256 uniform 1.5-unit blocks -> makespan 1.5.
__global__ __launch_bounds__(512, 2)
void gemm_fused(const short* __restrict__ A0, const short* __restrict__ B0,
                short* __restrict__ C0,
                const short* __restrict__ A1, const short* __restrict__ B1,
                short* __restrict__ C1) {
    __shared__ __align__(16) short lds[65536];   // 128 KB: 2 bufs x (A 32KB | B 32KB)
    const int t = threadIdx.x, l = t & 63, wv = t >> 6;
    const int lane16 = l & 15, quad = l >> 4;
    const int wm = wv >> 2, wn = wv & 3;         // 2 x 4 wave grid

    // XCD-chunked bijective swizzle (256 = 8 x 32)
    int bid = blockIdx.x;
    int wg = (bid & 7) * 32 + (bid >> 3);
    const int bm = wg & 31, bn = wg >> 5;        // QK: 32 x 8 tiles of 256^2

    const int grow = t >> 3;                     // 0..63
    const int lsl  = ((t & 7) ^ ((t >> 3) & 7)) * 8;   // inverse-swizzled slot
    const short* gA = A0 + (size_t)(bm * 256 + grow) * 1024 + lsl;
    const short* gB = B0 + (size_t)(bn * 256 + grow) * 1024 + lsl;

#define STAGE8(gsrc, matOff, half, j, T, buf)                                   \
    GLDS16((gsrc) + ((half) * 128 + (j) * 64) * 1024 + (T) * 64,                \
           lds + (buf) * 32768 + (matOff) + (half) * 8192 + (j) * 4096 + wv * 512)

    const int fsw0 = ((quad)     ^ (lane16 & 7)) * 8;
    const int fsw1 = ((quad + 4) ^ (lane16 & 7)) * 8;
    const int aoff = (wm * 128 + lane16) * 64;
    const int boff = (wn * 64  + lane16) * 64;

    f32x4 acc[8][4] = {};

    // ---- phase A prologue: tile0 all + tile1 A-lo ----
    STAGE8(gA, 0,     0, 0, 0, 0); STAGE8(gA, 0,     0, 1, 0, 0);
    STAGE8(gA, 0,     1, 0, 0, 0); STAGE8(gA, 0,     1, 1, 0, 0);
    STAGE8(gB, 16384, 0, 0, 0, 0); STAGE8(gB, 16384, 0, 1, 0, 0);
    STAGE8(gB, 16384, 1, 0, 0, 0); STAGE8(gB, 16384, 1, 1, 0, 0);
    STAGE8(gA, 0,     0, 0, 1, 1); STAGE8(gA, 0,     0, 1, 1, 1);
    asm volatile("s_waitcnt vmcnt(2)" ::: "memory");
    __builtin_amdgcn_s_barrier();

#define ARD(MI0)                                                                \
    a0 = *(const bf16x8*)(sAc + aoff + (MI0) * 1024 + fsw0);                    \
    a1 = *(const bf16x8*)(sAc + aoff + (MI0) * 1024 + fsw1);                    \
    a2 = *(const bf16x8*)(sAc + aoff + ((MI0) + 1) * 1024 + fsw0);              \
    a3 = *(const bf16x8*)(sAc + aoff + ((MI0) + 1) * 1024 + fsw1);

#define MFQ(MI0)                                                                \
    __builtin_amdgcn_s_setprio(1);                                              \
    _Pragma("unroll")                                                           \
    for (int nj = 0; nj < 4; ++nj) {                                            \
        acc[MI0][nj]       = mfma32k(a0, bf[nj][0], acc[MI0][nj]);              \
        acc[MI0][nj]       = mfma32k(a1, bf[nj][1], acc[MI0][nj]);              \
        acc[(MI0) + 1][nj] = mfma32k(a2, bf[nj][0], acc[(MI0) + 1][nj]);        \
        acc[(MI0) + 1][nj] = mfma32k(a3, bf[nj][1], acc[(MI0) + 1][nj]);        \
    }                                                                           \
    __builtin_amdgcn_s_setprio(0);

    for (int T = 0; T < 16; ++T) {
        const int cur = T & 1, nxt = cur ^ 1;
        const short* sAc = lds + cur * 32768;
        const short* sBc = sAc + 16384;
        bf16x8 bf[4][2];
#pragma unroll
        for (int nj = 0; nj < 4; ++nj) {
            bf[nj][0] = *(const bf16x8*)(sBc + boff + nj * 1024 + fsw0);
            bf[nj][1] = *(const bf16x8*)(sBc + boff + nj * 1024 + fsw1);
        }
        bf16x8 a0, a1, a2, a3;
        ARD(0)
        if (T < 15) { STAGE8(gA, 0, 1, 0, T + 1, nxt); STAGE8(gA, 0, 1, 1, T + 1, nxt); }
        __builtin_amdgcn_s_barrier();
        MFQ(0)
        __builtin_amdgcn_s_barrier();
        ARD(2)
        if (T < 15) { STAGE8(gB, 16384, 0, 0, T + 1, nxt); STAGE8(gB, 16384, 0, 1, T + 1, nxt); }
        __builtin_amdgcn_s_barrier();
        MFQ(2)
        __builtin_amdgcn_s_barrier();
        ARD(4)
        if (T < 15) { STAGE8(gB, 16384, 1, 0, T + 1, nxt); STAGE8(gB, 16384, 1, 1, T + 1, nxt); }
        __builtin_amdgcn_s_barrier();
        MFQ(4)
        __builtin_amdgcn_s_barrier();
        ARD(6)
        __builtin_amdgcn_s_barrier();
        MFQ(6)
        __builtin_amdgcn_s_barrier();
        if (T < 14) {
            STAGE8(gA, 0, 0, 0, T + 2, cur); STAGE8(gA, 0, 0, 1, T + 2, cur);
            asm volatile("s_waitcnt vmcnt(2)" ::: "memory");
            __builtin_amdgcn_s_barrier();
        } else if (T == 14) {
            asm volatile("s_waitcnt vmcnt(0)" ::: "memory");
            __builtin_amdgcn_s_barrier();
        }
    }
#undef ARD
#undef MFQ
#undef STAGE8

    // ---- epilogue A (no perm) ----
#pragma unroll
    for (int mi = 0; mi < 8; ++mi)
#pragma unroll
        for (int nj = 0; nj < 4; ++nj) {
            int row = bm * 256 + wm * 128 + mi * 16 + quad * 4;
            int col = bn * 256 + wn * 64 + nj * 16 + lane16;
#pragma unroll
            for (int r = 0; r < 4; ++r)
                C0[(size_t)(row + r) * 2048 + col] = f2bf(acc[mi][nj][r]);
        }

    // ---- phase B: VT 256x128 half-tile (4 x 64 = 256 of them) ----
    const int vbm = wg & 3, vbn = wg >> 2;
    const short* hA = A1 + (size_t)(vbm * 256 + grow) * 1024 + lsl;
    const short* hB = B1 + (size_t)(vbn * 128 + grow) * 1024 + lsl;
    f32x4 accB[8][2] = {};
    gemm_pipe_256x128(lds, hA, hB, wv, lane16, wn, fsw0, fsw1, aoff, accB);

    const int sEven = (lane16 >> 2) * 8 + (lane16 & 3);   // kv-perm within 32-col blocks
#pragma unroll
    for (int mi = 0; mi < 8; ++mi)
#pragma unroll
        for (int nj = 0; nj < 2; ++nj) {
            int row = vbm * 256 + wm * 128 + mi * 16 + quad * 4;
            int col = vbn * 128 + wn * 32 + nj * 16 + lane16;
            col = (col & ~31) | (sEven + (nj & 1) * 4);
#pragma unroll
            for (int r = 0; r < 4; ++r)
                C1[(size_t)(row + r) * 8192 + col] = f2bf(accB[mi][nj][r]);
        }
}

// ---------- output projection GEMM: out[8192][1024] f32 = CTX @ Wo^T + bo ----------
// R11: same 256x128-tile pipeline; grid 32x8 = 256 blocks = exactly one round.
__global__ __launch_bounds__(512, 2)
void gemm_out(const short* __restrict__ A, const short* __restrict__ Bm,
              float* __restrict__ C, const float* __restrict__ bias) {
    __shared__ __align__(16) short lds[65536];
    const int t = threadIdx.x, l = t & 63, wv = t >> 6;
    const int lane16 = l & 15, quad = l >> 4;
    const int wm = wv >> 2, wn = wv & 3;

    int bid = blockIdx.x;
    int wg = (bid & 7) * 32 + (bid >> 3);        // bijective XCD chunking
    const int bm = wg >> 3, bn = wg & 7;         // 32 x 8 tiles of 256x128

    const int grow = t >> 3;
    const int lsl  = ((t & 7) ^ ((t >> 3) & 7)) * 8;
    const short* hA = A  + (size_t)(bm * 256 + grow) * 1024 + lsl;
    const short* hB = Bm + (size_t)(bn * 128 + grow) * 1024 + lsl;

    const int fsw0 = ((quad)     ^ (lane16 & 7)) * 8;
    const int fsw1 = ((quad + 4) ^ (lane16 & 7)) * 8;
    const int aoff = (wm * 128 + lane16) * 64;

    f32x4 acc[8][2] = {};
    gemm_pipe_256x128(lds, hA, hB, wv, lane16, wn, fsw0, fsw1, aoff, acc);

#pragma unroll
    for (int mi = 0; mi < 8; ++mi)
#pragma unroll
        for (int nj = 0; nj < 2; ++nj) {
            int row = bm * 256 + wm * 128 + mi * 16 + quad * 4;
            int col = bn * 128 + wn * 32 + nj * 16 + lane16;
            float bv = bias[col];
#pragma unroll
            for (int r = 0; r < 4; ++r)
                C[(size_t)(row + r) * 1024 + col] = acc[mi][nj][r] + bv;
        }
}

// ---------- flash attention ----------
// QK[M][2048] bf16 (Q pre-scaled by CL2 | K), VT[1024][8192] bf16 (V^T, kv-permuted
// within 32-blocks), CTX[M][1024] bf16.
// S^T = K Q^T (P^T C-layout == A-frag layout), softmax without online max
// (scores provably bounded), P packed in-register via v_perm, PV via K=32 MFMA.
// Softmax denominator accumulated on the MATRIX pipe: lacc = mfma(P, ones, lacc).
//
// R5: T2 slot-swizzle -> bank conflicts 8.45M -> 0 (verified), timing neutral.
// R7: 2-deep QK(a+1)||PV(a) pipeline + setprio: 77.0 -> 75.8 (+1.5%). Kept.
// R10 diagnostic split reverted (cost ~6us). attn ~900 TF = m214 structural
// plateau; frozen.
__global__ __launch_bounds__(256, 4)
void attn_kernel(const short* __restrict__ QK, const short* __restrict__ VT,
                 short* __restrict__ CTX, int bh0) {
    __shared__ __align__(16) short sK[8192];
    __shared__ __align__(16) short sV[8192];
    const int t = threadIdx.x, w = t >> 6, l = t & 63;
    const int lane16 = l & 15, quad = l >> 4;
    const int bh = blockIdx.x + bh0, qt = blockIdx.y;
    const int b = bh >> 4, h = bh & 15;

    const int qx8 = (quad ^ ((lane16 >> 1) & 3)) * 8;

    const short* Qb = QK + ((size_t)(b * 2048 + qt * 128)) * 2048 + h * 64;
    const short* Vb = VT + ((size_t)(h * 64)) * 8192 + (size_t)b * 2048;
    const int ldsOff = (w * 64) * 8;

    int off_kq[4], off_v[4];
#pragma unroll
    for (int p = 0; p < 4; ++p) {
        int c = p * 256 + t;
        int sw = ((c & 3) ^ ((c >> 3) & 3)) * 8;
        off_kq[p] = ((c >> 2) & 127) * 2048 + (c >> 9) * 32 + sw;
        off_v[p]  = ((c >> 2) & 63) * 8192 + (c >> 8) * 32 + sw;
    }

#pragma unroll
    for (int p = 0; p < 4; ++p)
        GLDS16(Qb + off_kq[p], sK + p * 2048 + ldsOff);
    __syncthreads();
    bf16x8 qf[2][2];
#pragma unroll
    for (int mt = 0; mt < 2; ++mt)
#pragma unroll
        for (int ks = 0; ks < 2; ++ks)
            qf[mt][ks] = *(const bf16x8*)(sK + ks * 4096 + (w * 32 + mt * 16 + lane16) * 32 + qx8);
    __syncthreads();

    const short one = (short)0x3F80;
    const bf16x8 ONE8 = {one, one, one, one, one, one, one, one};
    f32x4 lacc[2] = {};
    f32x4 o[2][4] = {};

    const short* kptr = QK + ((size_t)(b * 2048)) * 2048 + 1024 + h * 64;
    const short* vptr = Vb;

    auto QKB = [&](int a, f32x4 (&sc)[2][2]) {
        __builtin_amdgcn_s_setprio(1);
#pragma unroll
        for (int sub = 0; sub < 2; ++sub) {
            int nt = a * 2 + sub;
            bf16x8 kf0 = *(const bf16x8*)(sK + (nt * 16 + lane16) * 32 + qx8);
            bf16x8 kf1 = *(const bf16x8*)(sK + 4096 + (nt * 16 + lane16) * 32 + qx8);
#pragma unroll
            for (int mt = 0; mt < 2; ++mt) {
                f32x4 z = {};
                z = mfma32k(kf0, qf[mt][0], z);
                z = mfma32k(kf1, qf[mt][1], z);
                sc[mt][sub] = z;
            }
        }
        __builtin_amdgcn_s_setprio(0);
    };
    auto PVB = [&](int a, f32x4 (&sc)[2][2]) {
        bf16x8 pf[2];
#pragma unroll
        for (int mt = 0; mt < 2; ++mt) {
            union { int i[4]; bf16x8 v; } u;
#pragma unroll
            for (int sub = 0; sub < 2; ++sub) {
                f32x4 e;
#pragma unroll
                for (int r = 0; r < 4; ++r)
                    e[r] = __builtin_amdgcn_exp2f(sc[mt][sub][r]);
                u.i[sub * 2]     = pack2(e[0], e[1]);
                u.i[sub * 2 + 1] = pack2(e[2], e[3]);
            }
            pf[mt] = u.v;
        }
        __builtin_amdgcn_s_setprio(1);
#pragma unroll
        for (int mt = 0; mt < 2; ++mt)
            lacc[mt] = mfma32k(pf[mt], ONE8, lacc[mt]);
#pragma unroll
        for (int dt = 0; dt < 4; ++dt) {
            bf16x8 vf = *(const bf16x8*)(sV + a * 2048 + (dt * 16 + lane16) * 32 + qx8);
#pragma unroll
            for (int mt = 0; mt < 2; ++mt)
                o[mt][dt] = mfma32k(pf[mt], vf, o[mt][dt]);
        }
        __builtin_amdgcn_s_setprio(0);
    };

    for (int kt = 0; kt < 16; ++kt) {
#pragma unroll
        for (int p = 0; p < 4; ++p)
            GLDS16(kptr + off_kq[p], sK + p * 2048 + ldsOff);
#pragma unroll
        for (int p = 0; p < 4; ++p)
            GLDS16(vptr + off_v[p], sV + p * 2048 + ldsOff);
        kptr += (size_t)128 * 2048;
        vptr += 128;
        __syncthreads();

        f32x4 scA[2][2], scB[2][2];
        QKB(0, scA);
        QKB(1, scB);  PVB(0, scA);
        QKB(2, scA);  PVB(1, scB);
        QKB(3, scB);  PVB(2, scA);
                      PVB(3, scB);
        __syncthreads();
    }

#pragma unroll
    for (int mt = 0; mt < 2; ++mt)
#pragma unroll
        for (int r = 0; r < 4; ++r) {
            float inv = 1.0f / lacc[mt][r];
            int row = b * 2048 + qt * 128 + w * 32 + mt * 16 + quad * 4 + r;
#pragma unroll
            for (int dt = 0; dt < 4; ++dt)
                CTX[(size_t)row * 1024 + h * 64 + dt * 16 + lane16] = f2bf(o[mt][dt][r] * inv);
        }
}

// ---------- launch ----------
extern "C" void kernel_launch(void* const* d_in, const int* in_sizes, int n_in,
                              void* d_out, int out_size, void* d_ws, size_t ws_size,
                              hipStream_t stream) {
    const float* X  = (const float*)d_in[0];
    const float* Wq = (const float*)d_in[1];
    const float* Wk = (const float*)d_in[2];
    const float* Wv = (const float*)d_in[3];
    const float* Wo = (const float*)d_in[4];
    const float* bo = (const float*)d_in[5];
    float* out = (float*)d_out;

    char* ws = (char*)d_ws;
    constexpr size_t OFF_XB  = 0;                                   // 16 MB
    constexpr size_t OFF_WQK = OFF_XB  + (size_t)Mrows * Ee * 2;    //  4 MB
    constexpr size_t OFF_WV  = OFF_WQK + (size_t)2 * Ee * Ee * 2;   //  2 MB
    constexpr size_t OFF_WO  = OFF_WV  + (size_t)Ee * Ee * 2;       //  2 MB
    constexpr size_t OFF_QK  = OFF_WO  + (size_t)Ee * Ee * 2;       // 32 MB
    constexpr size_t OFF_VT  = OFF_QK  + (size_t)Mrows * 2048 * 2;  // 16 MB
    constexpr size_t OFF_CTX = OFF_VT  + (size_t)Ee * Mrows * 2;    // 16 MB
    short* Xb   = (short*)(ws + OFF_XB);
    short* Wqk  = (short*)(ws + OFF_WQK);
    short* Wvb  = (short*)(ws + OFF_WV);
    short* Wob  = (short*)(ws + OFF_WO);
    short* QKb  = (short*)(ws + OFF_QK);
    short* VTb  = (short*)(ws + OFF_VT);
    short* CTX  = (short*)(ws + OFF_CTX);

    // all converts in one launch (X, Wq*CL2 | Wk, Wv, Wo)
    cvt_all<<<12288, 256, 0, stream>>>(X, Wq, Wk, Wv, Wo, Xb, Wqk, Wvb, Wob);

    // persistent 256-block fused GEMM: QK 256^2 tile + VT 256x128 half-tile each
    gemm_fused<<<256, 512, 0, stream>>>(Xb, Wqk, QKb, Wvb, Xb, VTb);

    // attention: CTX [8192][1024] bf16 (single dispatch)
    attn_kernel<<<dim3(Bb * Hh, Ss / 128), 256, 0, stream>>>(QKb, VTb, CTX, 0);

    // output projection + bias: f32 out (256 blocks = one round)
    gemm_out<<<256, 512, 0, stream>>>(CTX, Wob, out, bo);
}

// Round 8
// 243.046 us; speedup vs baseline: 1.0625x; 1.0233x over previous
//
#include <hip/hip_runtime.h>
#include <hip/hip_bf16.h>

// ---------- types ----------
typedef short bf16x8 __attribute__((ext_vector_type(8)));
typedef float f32x4  __attribute__((ext_vector_type(4)));

__device__ __forceinline__ short f2bf(float f) {
    union { float f; unsigned u; } x; x.f = f;
    unsigned r = x.u + 0x7fffu + ((x.u >> 16) & 1u);   // RTNE
    return (short)(r >> 16);
}

// round-half-up bf16 in top 16 bits (max err = half ULP, no coherent bias)
__device__ __forceinline__ unsigned rbits(float f) {
    union { float f; unsigned u; } x; x.f = f;
    return x.u + 0x8000u;
}
// pack 2 f32 -> 2 bf16 (lo=a, hi=b): one v_perm_b32 selecting top halves.
__device__ __forceinline__ int pack2(float a, float b) {
    return (int)__builtin_amdgcn_perm(rbits(b), rbits(a), 0x07060302u);
}

__device__ __forceinline__ f32x4 mfma32k(bf16x8 a, bf16x8 b, f32x4 c) {
    return __builtin_amdgcn_mfma_f32_16x16x32_bf16(a, b, c, 0, 0, 0);
}

#define GLDS16(g, l)                                                            \
    __builtin_amdgcn_global_load_lds(                                           \
        (const __attribute__((address_space(1))) void*)(g),                     \
        (__attribute__((address_space(3))) void*)(l), 16, 0, 0)

// ---------- problem constants ----------
static constexpr int Bb = 4, Ss = 2048, Ee = 1024, Hh = 16, Dd = 64;
static constexpr int Mrows = Bb * Ss;          // 8192
static constexpr float CL2 = 0.1803368801111204f;  // log2(e)/sqrt(D)

// ---------- fused fp32 -> bf16 convert (X + 4 weights; Wq pre-scaled by CL2) ----------
__global__ void cvt_all(const float* __restrict__ X,  const float* __restrict__ Wq,
                        const float* __restrict__ Wk, const float* __restrict__ Wv,
                        const float* __restrict__ Wo,
                        short* __restrict__ Xb, short* __restrict__ Wqk,
                        short* __restrict__ Wvb, short* __restrict__ Wob) {
    int bid = blockIdx.x;
    const float* src; short* dst; int off; float scale = 1.0f;
    if (bid < 8192) {                      // X: 8192 blocks
        src = X; dst = Xb; off = bid * 1024;
    } else {
        int wsel = (bid - 8192) >> 10;     // 1024 blocks per weight
        off = ((bid - 8192) & 1023) * 1024;
        if      (wsel == 0) { src = Wq; dst = Wqk;                scale = CL2; }
        else if (wsel == 1) { src = Wk; dst = Wqk + Ee * Ee; }
        else if (wsel == 2) { src = Wv; dst = Wvb; }
        else                { src = Wo; dst = Wob; }
    }
    int i = off + threadIdx.x * 4;
    float4 v = *(const float4*)(src + i);
    short4 o;
    o.x = f2bf(v.x * scale); o.y = f2bf(v.y * scale);
    o.z = f2bf(v.z * scale); o.w = f2bf(v.w * scale);
    *(short4*)(dst + i) = o;
}

// ---------- shared 256x128-tile 8-wave pipeline (R12: square wave-tiles) ----------
// R11's 2(M)x4(N) wave grid (128x32/wave, 8mi x 2nj) issued 20 frag-reads per
// 32 MFMAs -> LDS-read-bound (160 b128/CU/K-tile ~ 1920cy vs 1240cy MFMA, m134).
// R12: 4(M)x2(N) grid, 64x64/wave (4mi x 4nj) -> 16 reads per 32 MFMAs (-20%
// on the bound resource). Staging/barrier/vmcnt schedule UNCHANGED from R11;
// k ascending -> bit-identical accumulation.
// Hazard ledger: stage into a buf only after the barrier ending all reads of
// it; reads of tile T+1 sit behind boundary vmcnt(2)+barrier whose last-2
// outstanding are T+2's A-lo; prior global STORES in the vmcnt stream only
// make the wait stricter (safe).
__device__ __forceinline__ void gemm_pipe_256x128(
    short* lds, const short* hA, const short* hB,
    int wv, int lane16, int fsw0, int fsw1,
    f32x4 (&acc)[4][4])
{
#define STG(gsrc, matOff, half, j, T, buf)                                      \
    GLDS16((gsrc) + ((half) * 128 + (j) * 64) * 1024 + (T) * 64,                \
           lds + (buf) * 32768 + (matOff) + (half) * 8192 + (j) * 4096 + wv * 512)

    // prologue: T0 A(4)+B(2); T1 A-lo(2); keep last 2 in flight
    STG(hA, 0,     0, 0, 0, 0); STG(hA, 0,     0, 1, 0, 0);
    STG(hA, 0,     1, 0, 0, 0); STG(hA, 0,     1, 1, 0, 0);
    STG(hB, 16384, 0, 0, 0, 0); STG(hB, 16384, 0, 1, 0, 0);
    STG(hA, 0,     0, 0, 1, 1); STG(hA, 0,     0, 1, 1, 1);
    asm volatile("s_waitcnt vmcnt(2)" ::: "memory");
    __builtin_amdgcn_s_barrier();

    const int wm2 = wv & 3, wn2 = wv >> 2;       // 4 M x 2 N wave grid
    const int aoff = (wm2 * 64 + lane16) * 64;
    const int boff = (wn2 * 64 + lane16) * 64;

    for (int T = 0; T < 16; ++T) {
        const int cur = T & 1, nxt = cur ^ 1;
        const short* sAc = lds + cur * 32768;
        const short* sBc = sAc + 16384;
        bf16x8 bb[4][2];
#pragma unroll
        for (int nj = 0; nj < 4; ++nj) {
            bb[nj][0] = *(const bf16x8*)(sBc + boff + nj * 1024 + fsw0);
            bb[nj][1] = *(const bf16x8*)(sBc + boff + nj * 1024 + fsw1);
        }
        bf16x8 a0, a1, a2, a3;
        // ---- phase 0: mi 0,1; stage A-hi(T+1) + B(T+1) ----
        a0 = *(const bf16x8*)(sAc + aoff + 0 * 1024 + fsw0);
        a1 = *(const bf16x8*)(sAc + aoff + 0 * 1024 + fsw1);
        a2 = *(const bf16x8*)(sAc + aoff + 1 * 1024 + fsw0);
        a3 = *(const bf16x8*)(sAc + aoff + 1 * 1024 + fsw1);
        if (T < 15) {
            STG(hA, 0,     1, 0, T + 1, nxt); STG(hA, 0,     1, 1, T + 1, nxt);
            STG(hB, 16384, 0, 0, T + 1, nxt); STG(hB, 16384, 0, 1, T + 1, nxt);
        }
        __builtin_amdgcn_s_barrier();
        __builtin_amdgcn_s_setprio(1);
#pragma unroll
        for (int nj = 0; nj < 4; ++nj) {
            acc[0][nj] = mfma32k(a0, bb[nj][0], acc[0][nj]);
            acc[0][nj] = mfma32k(a1, bb[nj][1], acc[0][nj]);
            acc[1][nj] = mfma32k(a2, bb[nj][0], acc[1][nj]);
            acc[1][nj] = mfma32k(a3, bb[nj][1], acc[1][nj]);
        }
        __builtin_amdgcn_s_setprio(0);
        __builtin_amdgcn_s_barrier();
        // ---- phase 1: mi 2,3 ----
        a0 = *(const bf16x8*)(sAc + aoff + 2 * 1024 + fsw0);
        a1 = *(const bf16x8*)(sAc + aoff + 2 * 1024 + fsw1);
        a2 = *(const bf16x8*)(sAc + aoff + 3 * 1024 + fsw0);
        a3 = *(const bf16x8*)(sAc + aoff + 3 * 1024 + fsw1);
        __builtin_amdgcn_s_barrier();
        __builtin_amdgcn_s_setprio(1);
#pragma unroll
        for (int nj = 0; nj < 4; ++nj) {
            acc[2][nj] = mfma32k(a0, bb[nj][0], acc[2][nj]);
            acc[2][nj] = mfma32k(a1, bb[nj][1], acc[2][nj]);
            acc[3][nj] = mfma32k(a2, bb[nj][0], acc[3][nj]);
            acc[3][nj] = mfma32k(a3, bb[nj][1], acc[3][nj]);
        }
        __builtin_amdgcn_s_setprio(0);
        __builtin_amdgcn_s_barrier();
        // ---- boundary: pre-issue A-lo(T+2) into cur, counted wait ----
        if (T < 14) {
            STG(hA, 0, 0, 0, T + 2, cur); STG(hA, 0, 0, 1, T + 2, cur);
            asm volatile("s_waitcnt vmcnt(2)" ::: "memory");
            __builtin_amdgcn_s_barrier();
        } else if (T == 14) {
            asm volatile("s_waitcnt vmcnt(0)" ::: "memory");
            __builtin_amdgcn_s_barrier();
        }
    }
#undef STG
}

// ---------- fused projection GEMMs: persistent 256-block grid (R11/R12) ----------
// Each block: (phase A) one 256^2 QK tile  C0[8192][2048] = Xb @ Wqk^T
//             (phase B) one 256x128 VT half-tile C1[1024][8192] = Wvb @ Xb^T
//                       (kv-permuted within 32-col blocks, for attn PV)
__global__ __launch_bounds__(512, 2)
void gemm_fused(const short* __restrict__ A0, const short* __restrict__ B0,
                short* __restrict__ C0,
                const short* __restrict__ A1, const short* __restrict__ B1,
                short* __restrict__ C1) {
    __shared__ __align__(16) short lds[65536];   // 128 KB: 2 bufs x (A 32KB | B 32KB)
    const int t = threadIdx.x, l = t & 63, wv = t >> 6;
    const int lane16 = l & 15, quad = l >> 4;
    const int wm = wv >> 2, wn = wv & 3;         // 2 x 4 wave grid (phase A)

    // XCD-chunked bijective swizzle (256 = 8 x 32)
    int bid = blockIdx.x;
    int wg = (bid & 7) * 32 + (bid >> 3);
    const int bm = wg & 31, bn = wg >> 5;        // QK: 32 x 8 tiles of 256^2

    const int grow = t >> 3;                     // 0..63
    const int lsl  = ((t & 7) ^ ((t >> 3) & 7)) * 8;   // inverse-swizzled slot
    const short* gA = A0 + (size_t)(bm * 256 + grow) * 1024 + lsl;
    const short* gB = B0 + (size_t)(bn * 256 + grow) * 1024 + lsl;

#define STAGE8(gsrc, matOff, half, j, T, buf)                                   \
    GLDS16((gsrc) + ((half) * 128 + (j) * 64) * 1024 + (T) * 64,                \
           lds + (buf) * 32768 + (matOff) + (half) * 8192 + (j) * 4096 + wv * 512)

    const int fsw0 = ((quad)     ^ (lane16 & 7)) * 8;
    const int fsw1 = ((quad + 4) ^ (lane16 & 7)) * 8;
    const int aoff = (wm * 128 + lane16) * 64;
    const int boff = (wn * 64  + lane16) * 64;

    f32x4 acc[8][4] = {};

    // ---- phase A prologue: tile0 all + tile1 A-lo ----
    STAGE8(gA, 0,     0, 0, 0, 0); STAGE8(gA, 0,     0, 1, 0, 0);
    STAGE8(gA, 0,     1, 0, 0, 0); STAGE8(gA, 0,     1, 1, 0, 0);
    STAGE8(gB, 16384, 0, 0, 0, 0); STAGE8(gB, 16384, 0, 1, 0, 0);
    STAGE8(gB, 16384, 1, 0, 0, 0); STAGE8(gB, 16384, 1, 1, 0, 0);
    STAGE8(gA, 0,     0, 0, 1, 1); STAGE8(gA, 0,     0, 1, 1, 1);
    asm volatile("s_waitcnt vmcnt(2)" ::: "memory");
    __builtin_amdgcn_s_barrier();

#define ARD(MI0)                                                                \
    a0 = *(const bf16x8*)(sAc + aoff + (MI0) * 1024 + fsw0);                    \
    a1 = *(const bf16x8*)(sAc + aoff + (MI0) * 1024 + fsw1);                    \
    a2 = *(const bf16x8*)(sAc + aoff + ((MI0) + 1) * 1024 + fsw0);              \
    a3 = *(const bf16x8*)(sAc + aoff + ((MI0) + 1) * 1024 + fsw1);

#define MFQ(MI0)                                                                \
    __builtin_amdgcn_s_setprio(1);                                              \
    _Pragma("unroll")                                                           \
    for (int nj = 0; nj < 4; ++nj) {                                            \
        acc[MI0][nj]       = mfma32k(a0, bf[nj][0], acc[MI0][nj]);              \
        acc[MI0][nj]       = mfma32k(a1, bf[nj][1], acc[MI0][nj]);              \
        acc[(MI0) + 1][nj] = mfma32k(a2, bf[nj][0], acc[(MI0) + 1][nj]);        \
        acc[(MI0) + 1][nj] = mfma32k(a3, bf[nj][1], acc[(MI0) + 1][nj]);        \
    }                                                                           \
    __builtin_amdgcn_s_setprio(0);

    for (int T = 0; T < 16; ++T) {
        const int cur = T & 1, nxt = cur ^ 1;
        const short* sAc = lds + cur * 32768;
        const short* sBc = sAc + 16384;
        bf16x8 bf[4][2];
#pragma unroll
        for (int nj = 0; nj < 4; ++nj) {
            bf[nj][0] = *(const bf16x8*)(sBc + boff + nj * 1024 + fsw0);
            bf[nj][1] = *(const bf16x8*)(sBc + boff + nj * 1024 + fsw1);
        }
        bf16x8 a0, a1, a2, a3;
        ARD(0)
        if (T < 15) { STAGE8(gA, 0, 1, 0, T + 1, nxt); STAGE8(gA, 0, 1, 1, T + 1, nxt); }
        __builtin_amdgcn_s_barrier();
        MFQ(0)
        __builtin_amdgcn_s_barrier();
        ARD(2)
        if (T < 15) { STAGE8(gB, 16384, 0, 0, T + 1, nxt); STAGE8(gB, 16384, 0, 1, T + 1, nxt); }
        __builtin_amdgcn_s_barrier();
        MFQ(2)
        __builtin_amdgcn_s_barrier();
        ARD(4)
        if (T < 15) { STAGE8(gB, 16384, 1, 0, T + 1, nxt); STAGE8(gB, 16384, 1, 1, T + 1, nxt); }
        __builtin_amdgcn_s_barrier();
        MFQ(4)
        __builtin_amdgcn_s_barrier();
        ARD(6)
        __builtin_amdgcn_s_barrier();
        MFQ(6)
        __builtin_amdgcn_s_barrier();
        if (T < 14) {
            STAGE8(gA, 0, 0, 0, T + 2, cur); STAGE8(gA, 0, 0, 1, T + 2, cur);
            asm volatile("s_waitcnt vmcnt(2)" ::: "memory");
            __builtin_amdgcn_s_barrier();
        } else if (T == 14) {
            asm volatile("s_waitcnt vmcnt(0)" ::: "memory");
            __builtin_amdgcn_s_barrier();
        }
    }
#undef ARD
#undef MFQ
#undef STAGE8

    // ---- epilogue A (no perm) ----
#pragma unroll
    for (int mi = 0; mi < 8; ++mi)
#pragma unroll
        for (int nj = 0; nj < 4; ++nj) {
            int row = bm * 256 + wm * 128 + mi * 16 + quad * 4;
            int col = bn * 256 + wn * 64 + nj * 16 + lane16;
#pragma unroll
            for (int r = 0; r < 4; ++r)
                C0[(size_t)(row + r) * 2048 + col] = f2bf(acc[mi][nj][r]);
        }

    // ---- phase B: VT 256x128 half-tile (4 x 64 = 256 of them) ----
    const int vbm = wg & 3, vbn = wg >> 2;
    const short* hA = A1 + (size_t)(vbm * 256 + grow) * 1024 + lsl;
    const short* hB = B1 + (size_t)(vbn * 128 + grow) * 1024 + lsl;
    f32x4 accB[4][4] = {};
    gemm_pipe_256x128(lds, hA, hB, wv, lane16, fsw0, fsw1, accB);

    const int wm2 = wv & 3, wn2 = wv >> 2;       // square wave grid (R12)
    const int sEven = (lane16 >> 2) * 8 + (lane16 & 3);   // kv-perm within 32-col blocks
#pragma unroll
    for (int mi = 0; mi < 4; ++mi)
#pragma unroll
        for (int nj = 0; nj < 4; ++nj) {
            int row = vbm * 256 + wm2 * 64 + mi * 16 + quad * 4;
            int col = vbn * 128 + wn2 * 64 + nj * 16 + lane16;
            col = (col & ~31) | (sEven + (nj & 1) * 4);
#pragma unroll
            for (int r = 0; r < 4; ++r)
                C1[(size_t)(row + r) * 8192 + col] = f2bf(accB[mi][nj][r]);
        }
}

// ---------- output projection GEMM: out[8192][1024] f32 = CTX @ Wo^T + bo ----------
// 256x128 tiles; grid 32x8 = 256 blocks = exactly one round. R12 square wave grid.
__global__ __launch_bounds__(512, 2)
void gemm_out(const short* __restrict__ A, const short* __restrict__ Bm,
              float* __restrict__ C, const float* __restrict__ bias) {
    __shared__ __align__(16) short lds[65536];
    const int t = threadIdx.x, l = t & 63, wv = t >> 6;
    const int lane16 = l & 15, quad = l >> 4;

    int bid = blockIdx.x;
    int wg = (bid & 7) * 32 + (bid >> 3);        // bijective XCD chunking
    const int bm = wg >> 3, bn = wg & 7;         // 32 x 8 tiles of 256x128

    const int grow = t >> 3;
    const int lsl  = ((t & 7) ^ ((t >> 3) & 7)) * 8;
    const short* hA = A  + (size_t)(bm * 256 + grow) * 1024 + lsl;
    const short* hB = Bm + (size_t)(bn * 128 + grow) * 1024 + lsl;

    const int fsw0 = ((quad)     ^ (lane16 & 7)) * 8;
    const int fsw1 = ((quad + 4) ^ (lane16 & 7)) * 8;

    f32x4 acc[4][4] = {};
    gemm_pipe_256x128(lds, hA, hB, wv, lane16, fsw0, fsw1, acc);

    const int wm2 = wv & 3, wn2 = wv >> 2;
#pragma unroll
    for (int mi = 0; mi < 4; ++mi)
#pragma unroll
        for (int nj = 0; nj < 4; ++nj) {
            int row = bm * 256 + wm2 * 64 + mi * 16 + quad * 4;
            int col = bn * 128 + wn2 * 64 + nj * 16 + lane16;
            float bv = bias[col];
#pragma unroll
            for (int r = 0; r < 4; ++r)
                C[(size_t)(row + r) * 1024 + col] = acc[mi][nj][r] + bv;
        }
}

// ---------- flash attention ----------
// QK[M][2048] bf16 (Q pre-scaled by CL2 | K), VT[1024][8192] bf16 (V^T, kv-permuted
// within 32-blocks), CTX[M][1024] bf16.
// S^T = K Q^T (P^T C-layout == A-frag layout), softmax without online max
// (scores provably bounded), P packed in-register via v_perm, PV via K=32 MFMA.
// Softmax denominator accumulated on the MATRIX pipe: lacc = mfma(P, ones, lacc).
//
// R12: DIAGNOSTIC split x2 again (bh0 = 0, 32) to surface post-R11 gemm_fused
// counters; known cost ~5us, revert next round. attn body frozen (m214 plateau).
__global__ __launch_bounds__(256, 4)
void attn_kernel(const short* __restrict__ QK, const short* __restrict__ VT,
                 short* __restrict__ CTX, int bh0) {
    __shared__ __align__(16) short sK[8192];
    __shared__ __align__(16) short sV[8192];
    const int t = threadIdx.x, w = t >> 6, l = t & 63;
    const int lane16 = l & 15, quad = l >> 4;
    const int bh = blockIdx.x + bh0, qt = blockIdx.y;
    const int b = bh >> 4, h = bh & 15;

    const int qx8 = (quad ^ ((lane16 >> 1) & 3)) * 8;

    const short* Qb = QK + ((size_t)(b * 2048 + qt * 128)) * 2048 + h * 64;
    const short* Vb = VT + ((size_t)(h * 64)) * 8192 + (size_t)b * 2048;
    const int ldsOff = (w * 64) * 8;

    int off_kq[4], off_v[4];
#pragma unroll
    for (int p = 0; p < 4; ++p) {
        int c = p * 256 + t;
        int sw = ((c & 3) ^ ((c >> 3) & 3)) * 8;
        off_kq[p] = ((c >> 2) & 127) * 2048 + (c >> 9) * 32 + sw;
        off_v[p]  = ((c >> 2) & 63) * 8192 + (c >> 8) * 32 + sw;
    }

#pragma unroll
    for (int p = 0; p < 4; ++p)
        GLDS16(Qb + off_kq[p], sK + p * 2048 + ldsOff);
    __syncthreads();
    bf16x8 qf[2][2];
#pragma unroll
    for (int mt = 0; mt < 2; ++mt)
#pragma unroll
        for (int ks = 0; ks < 2; ++ks)
            qf[mt][ks] = *(const bf16x8*)(sK + ks * 4096 + (w * 32 + mt * 16 + lane16) * 32 + qx8);
    __syncthreads();

    const short one = (short)0x3F80;
    const bf16x8 ONE8 = {one, one, one, one, one, one, one, one};
    f32x4 lacc[2] = {};
    f32x4 o[2][4] = {};

    const short* kptr = QK + ((size_t)(b * 2048)) * 2048 + 1024 + h * 64;
    const short* vptr = Vb;

    auto QKB = [&](int a, f32x4 (&sc)[2][2]) {
        __builtin_amdgcn_s_setprio(1);
#pragma unroll
        for (int sub = 0; sub < 2; ++sub) {
            int nt = a * 2 + sub;
            bf16x8 kf0 = *(const bf16x8*)(sK + (nt * 16 + lane16) * 32 + qx8);
            bf16x8 kf1 = *(const bf16x8*)(sK + 4096 + (nt * 16 + lane16) * 32 + qx8);
#pragma unroll
            for (int mt = 0; mt < 2; ++mt) {
                f32x4 z = {};
                z = mfma32k(kf0, qf[mt][0], z);
                z = mfma32k(kf1, qf[mt][1], z);
                sc[mt][sub] = z;
            }
        }
        __builtin_amdgcn_s_setprio(0);
    };
    auto PVB = [&](int a, f32x4 (&sc)[2][2]) {
        bf16x8 pf[2];
#pragma unroll
        for (int mt = 0; mt < 2; ++mt) {
            union { int i[4]; bf16x8 v; } u;
#pragma unroll
            for (int sub = 0; sub < 2; ++sub) {
                f32x4 e;
#pragma unroll
                for (int r = 0; r < 4; ++r)
                    e[r] = __builtin_amdgcn_exp2f(sc[mt][sub][r]);
                u.i[sub * 2]     = pack2(e[0], e[1]);
                u.i[sub * 2 + 1] = pack2(e[2], e[3]);
            }
            pf[mt] = u.v;
        }
        __builtin_amdgcn_s_setprio(1);
#pragma unroll
        for (int mt = 0; mt < 2; ++mt)
            lacc[mt] = mfma32k(pf[mt], ONE8, lacc[mt]);
#pragma unroll
        for (int dt = 0; dt < 4; ++dt) {
            bf16x8 vf = *(const bf16x8*)(sV + a * 2048 + (dt * 16 + lane16) * 32 + qx8);
#pragma unroll
            for (int mt = 0; mt < 2; ++mt)
                o[mt][dt] = mfma32k(pf[mt], vf, o[mt][dt]);
        }
        __builtin_amdgcn_s_setprio(0);
    };

    for (int kt = 0; kt < 16; ++kt) {
#pragma unroll
        for (int p = 0; p < 4; ++p)
            GLDS16(kptr + off_kq[p], sK + p * 2048 + ldsOff);
#pragma unroll
        for (int p = 0; p < 4; ++p)
            GLDS16(vptr + off_v[p], sV + p * 2048 + ldsOff);
        kptr += (size_t)128 * 2048;
        vptr += 128;
        __syncthreads();

        f32x4 scA[2][2], scB[2][2];
        QKB(0, scA);
        QKB(1, scB);  PVB(0, scA);
        QKB(2, scA);  PVB(1, scB);
        QKB(3, scB);  PVB(2, scA);
                      PVB(3, scB);
        __syncthreads();
    }

#pragma unroll
    for (int mt = 0; mt < 2; ++mt)
#pragma unroll
        for (int r = 0; r < 4; ++r) {
            float inv = 1.0f / lacc[mt][r];
            int row = b * 2048 + qt * 128 + w * 32 + mt * 16 + quad * 4 + r;
#pragma unroll
            for (int dt = 0; dt < 4; ++dt)
                CTX[(size_t)row * 1024 + h * 64 + dt * 16 + lane16] = f2bf(o[mt][dt][r] * inv);
        }
}

// ---------- launch ----------
extern "C" void kernel_launch(void* const* d_in, const int* in_sizes, int n_in,
                              void* d_out, int out_size, void* d_ws, size_t ws_size,
                              hipStream_t stream) {
    const float* X  = (const float*)d_in[0];
    const float* Wq = (const float*)d_in[1];
    const float* Wk = (const float*)d_in[2];
    const float* Wv = (const float*)d_in[3];
    const float* Wo = (const float*)d_in[4];
    const float* bo = (const float*)d_in[5];
    float* out = (float*)d_out;

    char* ws = (char*)d_ws;
    constexpr size_t OFF_XB  = 0;                                   // 16 MB
    constexpr size_t OFF_WQK = OFF_XB  + (size_t)Mrows * Ee * 2;    //  4 MB
    constexpr size_t OFF_WV  = OFF_WQK + (size_t)2 * Ee * Ee * 2;   //  2 MB
    constexpr size_t OFF_WO  = OFF_WV  + (size_t)Ee * Ee * 2;       //  2 MB
    constexpr size_t OFF_QK  = OFF_WO  + (size_t)Ee * Ee * 2;       // 32 MB
    constexpr size_t OFF_VT  = OFF_QK  + (size_t)Mrows * 2048 * 2;  // 16 MB
    constexpr size_t OFF_CTX = OFF_VT  + (size_t)Ee * Mrows * 2;    // 16 MB
    short* Xb   = (short*)(ws + OFF_XB);
    short* Wqk  = (short*)(ws + OFF_WQK);
    short* Wvb  = (short*)(ws + OFF_WV);
    short* Wob  = (short*)(ws + OFF_WO);
    short* QKb  = (short*)(ws + OFF_QK);
    short* VTb  = (short*)(ws + OFF_VT);
    short* CTX  = (short*)(ws + OFF_CTX);

    // all converts in one launch (X, Wq*CL2 | Wk, Wv, Wo)
    cvt_all<<<12288, 256, 0, stream>>>(X, Wq, Wk, Wv, Wo, Xb, Wqk, Wvb, Wob);

    // persistent 256-block fused GEMM: QK 256^2 tile + VT 256x128 half-tile each
    gemm_fused<<<256, 512, 0, stream>>>(Xb, Wqk, QKb, Wvb, Xb, VTb);

    // attention: CTX [8192][1024] bf16 -- R12 diagnostic split x2
    attn_kernel<<<dim3(32, Ss / 128), 256, 0, stream>>>(QKb, VTb, CTX, 0);
    attn_kernel<<<dim3(32, Ss / 128), 256, 0, stream>>>(QKb, VTb, CTX, 32);

    // output projection + bias: f32 out (256 blocks = one round)
    gemm_out<<<256, 512, 0, stream>>>(CTX, Wob, out, bo);
}

// Round 9
// 237.852 us; speedup vs baseline: 1.0857x; 1.0218x over previous
//
#include <hip/hip_runtime.h>
#include <hip/hip_bf16.h>

// ---------- types ----------
typedef short bf16x8 __attribute__((ext_vector_type(8)));
typedef float f32x4  __attribute__((ext_vector_type(4)));

__device__ __forceinline__ short f2bf(float f) {
    union { float f; unsigned u; } x; x.f = f;
    unsigned r = x.u + 0x7fffu + ((x.u >> 16) & 1u);   // RTNE
    return (short)(r >> 16);
}

// round-half-up bf16 in top 16 bits (max err = half ULP, no coherent bias)
__device__ __forceinline__ unsigned rbits(float f) {
    union { float f; unsigned u; } x; x.f = f;
    return x.u + 0x8000u;
}
// pack 2 f32 -> 2 bf16 (lo=a, hi=b): one v_perm_b32 selecting top halves.
__device__ __forceinline__ int pack2(float a, float b) {
    return (int)__builtin_amdgcn_perm(rbits(b), rbits(a), 0x07060302u);
}

__device__ __forceinline__ f32x4 mfma32k(bf16x8 a, bf16x8 b, f32x4 c) {
    return __builtin_amdgcn_mfma_f32_16x16x32_bf16(a, b, c, 0, 0, 0);
}

#define GLDS16(g, l)                                                            \
    __builtin_amdgcn_global_load_lds(                                           \
        (const __attribute__((address_space(1))) void*)(g),                     \
        (__attribute__((address_space(3))) void*)(l), 16, 0, 0)

// ---------- problem constants ----------
static constexpr int Bb = 4, Ss = 2048, Ee = 1024, Hh = 16, Dd = 64;
static constexpr int Mrows = Bb * Ss;          // 8192
static constexpr float CL2 = 0.1803368801111204f;  // log2(e)/sqrt(D)

// ---------- fused fp32 -> bf16 convert (X + 4 weights; Wq pre-scaled by CL2) ----------
__global__ void cvt_all(const float* __restrict__ X,  const float* __restrict__ Wq,
                        const float* __restrict__ Wk, const float* __restrict__ Wv,
                        const float* __restrict__ Wo,
                        short* __restrict__ Xb, short* __restrict__ Wqk,
                        short* __restrict__ Wvb, short* __restrict__ Wob) {
    int bid = blockIdx.x;
    const float* src; short* dst; int off; float scale = 1.0f;
    if (bid < 8192) {                      // X: 8192 blocks
        src = X; dst = Xb; off = bid * 1024;
    } else {
        int wsel = (bid - 8192) >> 10;     // 1024 blocks per weight
        off = ((bid - 8192) & 1023) * 1024;
        if      (wsel == 0) { src = Wq; dst = Wqk;                scale = CL2; }
        else if (wsel == 1) { src = Wk; dst = Wqk + Ee * Ee; }
        else if (wsel == 2) { src = Wv; dst = Wvb; }
        else                { src = Wo; dst = Wob; }
    }
    int i = off + threadIdx.x * 4;
    float4 v = *(const float4*)(src + i);
    short4 o;
    o.x = f2bf(v.x * scale); o.y = f2bf(v.y * scale);
    o.z = f2bf(v.z * scale); o.w = f2bf(v.w * scale);
    *(short4*)(dst + i) = o;
}

// ---------- shared 256x128-tile 8-wave pipeline (R12 square wave-tiles) ----------
// 4(M)x2(N) wave grid, 64x64/wave (4mi x 4nj): 16 frag-reads per 32 MFMAs.
// Double-buffered LDS, slot-swizzle phys=logical^(row&7) both sides (rule #21),
// counted vmcnt(2) at the tile boundary. k ascending -> bit-identical.
// Hazard ledger: stage into a buf only after the barrier ending all reads of
// it; reads of tile T+1 sit behind boundary vmcnt(2)+barrier whose last-2
// outstanding are T+2's A-lo; prior global STORES in the vmcnt stream only
// make the wait stricter (safe).
__device__ __forceinline__ void gemm_pipe_256x128(
    short* lds, const short* hA, const short* hB,
    int wv, int lane16, int fsw0, int fsw1,
    f32x4 (&acc)[4][4])
{
#define STG(gsrc, matOff, half, j, T, buf)                                      \
    GLDS16((gsrc) + ((half) * 128 + (j) * 64) * 1024 + (T) * 64,                \
           lds + (buf) * 32768 + (matOff) + (half) * 8192 + (j) * 4096 + wv * 512)

    // prologue: T0 A(4)+B(2); T1 A-lo(2); keep last 2 in flight
    STG(hA, 0,     0, 0, 0, 0); STG(hA, 0,     0, 1, 0, 0);
    STG(hA, 0,     1, 0, 0, 0); STG(hA, 0,     1, 1, 0, 0);
    STG(hB, 16384, 0, 0, 0, 0); STG(hB, 16384, 0, 1, 0, 0);
    STG(hA, 0,     0, 0, 1, 1); STG(hA, 0,     0, 1, 1, 1);
    asm volatile("s_waitcnt vmcnt(2)" ::: "memory");
    __builtin_amdgcn_s_barrier();

    const int wm2 = wv & 3, wn2 = wv >> 2;       // 4 M x 2 N wave grid
    const int aoff = (wm2 * 64 + lane16) * 64;
    const int boff = (wn2 * 64 + lane16) * 64;

    for (int T = 0; T < 16; ++T) {
        const int cur = T & 1, nxt = cur ^ 1;
        const short* sAc = lds + cur * 32768;
        const short* sBc = sAc + 16384;
        bf16x8 bb[4][2];
#pragma unroll
        for (int nj = 0; nj < 4; ++nj) {
            bb[nj][0] = *(const bf16x8*)(sBc + boff + nj * 1024 + fsw0);
            bb[nj][1] = *(const bf16x8*)(sBc + boff + nj * 1024 + fsw1);
        }
        bf16x8 a0, a1, a2, a3;
        // ---- phase 0: mi 0,1; stage A-hi(T+1) + B(T+1) ----
        a0 = *(const bf16x8*)(sAc + aoff + 0 * 1024 + fsw0);
        a1 = *(const bf16x8*)(sAc + aoff + 0 * 1024 + fsw1);
        a2 = *(const bf16x8*)(sAc + aoff + 1 * 1024 + fsw0);
        a3 = *(const bf16x8*)(sAc + aoff + 1 * 1024 + fsw1);
        if (T < 15) {
            STG(hA, 0,     1, 0, T + 1, nxt); STG(hA, 0,     1, 1, T + 1, nxt);
            STG(hB, 16384, 0, 0, T + 1, nxt); STG(hB, 16384, 0, 1, T + 1, nxt);
        }
        __builtin_amdgcn_s_barrier();
        __builtin_amdgcn_s_setprio(1);
#pragma unroll
        for (int nj = 0; nj < 4; ++nj) {
            acc[0][nj] = mfma32k(a0, bb[nj][0], acc[0][nj]);
            acc[0][nj] = mfma32k(a1, bb[nj][1], acc[0][nj]);
            acc[1][nj] = mfma32k(a2, bb[nj][0], acc[1][nj]);
            acc[1][nj] = mfma32k(a3, bb[nj][1], acc[1][nj]);
        }
        __builtin_amdgcn_s_setprio(0);
        __builtin_amdgcn_s_barrier();
        // ---- phase 1: mi 2,3 ----
        a0 = *(const bf16x8*)(sAc + aoff + 2 * 1024 + fsw0);
        a1 = *(const bf16x8*)(sAc + aoff + 2 * 1024 + fsw1);
        a2 = *(const bf16x8*)(sAc + aoff + 3 * 1024 + fsw0);
        a3 = *(const bf16x8*)(sAc + aoff + 3 * 1024 + fsw1);
        __builtin_amdgcn_s_barrier();
        __builtin_amdgcn_s_setprio(1);
#pragma unroll
        for (int nj = 0; nj < 4; ++nj) {
            acc[2][nj] = mfma32k(a0, bb[nj][0], acc[2][nj]);
            acc[2][nj] = mfma32k(a1, bb[nj][1], acc[2][nj]);
            acc[3][nj] = mfma32k(a2, bb[nj][0], acc[3][nj]);
            acc[3][nj] = mfma32k(a3, bb[nj][1], acc[3][nj]);
        }
        __builtin_amdgcn_s_setprio(0);
        __builtin_amdgcn_s_barrier();
        // ---- boundary: pre-issue A-lo(T+2) into cur, counted wait ----
        if (T < 14) {
            STG(hA, 0, 0, 0, T + 2, cur); STG(hA, 0, 0, 1, T + 2, cur);
            asm volatile("s_waitcnt vmcnt(2)" ::: "memory");
            __builtin_amdgcn_s_barrier();
        } else if (T == 14) {
            asm volatile("s_waitcnt vmcnt(0)" ::: "memory");
            __builtin_amdgcn_s_barrier();
        }
    }
#undef STG
}

// ---------- fused projection GEMMs: persistent 256-block grid ----------
// Each block: (phase A) one 256^2 QK tile  C0[8192][2048] = Xb @ Wqk^T
//             (phase B) one 256x128 VT half-tile C1[1024][8192] = Wvb @ Xb^T
//
// R13: rectangular XCD mapping. The old chunking gave XCD x the column-strip
// {all 32 bm} x {bn=x} -> each XCD streamed ALL 16MB of A through its 4MB L2
// (FETCH 84MB, miss-latency stalls at our ~1-tile pipeline depth). Now XCD x
// owns a 4(bm)x8(bn) rectangle: working set 4 A-panels (2MB) + B (4MB) ~ L2-
// resident. Phase B: XCD x owns {all 4 vbm} x {8 vbn}: Wvb 2MB + Xb-cols 2MB.
__global__ __launch_bounds__(512, 2)
void gemm_fused(const short* __restrict__ A0, const short* __restrict__ B0,
                short* __restrict__ C0,
                const short* __restrict__ A1, const short* __restrict__ B1,
                short* __restrict__ C1) {
    __shared__ __align__(16) short lds[65536];   // 128 KB: 2 bufs x (A 32KB | B 32KB)
    const int t = threadIdx.x, l = t & 63, wv = t >> 6;
    const int lane16 = l & 15, quad = l >> 4;
    const int wm = wv >> 2, wn = wv & 3;         // 2 x 4 wave grid (phase A)

    // R13 rectangular XCD mapping (bijective): xcd = bid&7, i = bid>>3
    int bid = blockIdx.x;
    const int xcd = bid & 7, ib = bid >> 3;      // 8 x 32
    const int bm = xcd * 4 + (ib & 3), bn = ib >> 2;   // 4x8 rect per XCD

    const int grow = t >> 3;                     // 0..63
    const int lsl  = ((t & 7) ^ ((t >> 3) & 7)) * 8;   // inverse-swizzled slot
    const short* gA = A0 + (size_t)(bm * 256 + grow) * 1024 + lsl;
    const short* gB = B0 + (size_t)(bn * 256 + grow) * 1024 + lsl;

#define STAGE8(gsrc, matOff, half, j, T, buf)                                   \
    GLDS16((gsrc) + ((half) * 128 + (j) * 64) * 1024 + (T) * 64,                \
           lds + (buf) * 32768 + (matOff) + (half) * 8192 + (j) * 4096 + wv * 512)

    const int fsw0 = ((quad)     ^ (lane16 & 7)) * 8;
    const int fsw1 = ((quad + 4) ^ (lane16 & 7)) * 8;
    const int aoff = (wm * 128 + lane16) * 64;
    const int boff = (wn * 64  + lane16) * 64;

    f32x4 acc[8][4] = {};

    // ---- phase A prologue: tile0 all + tile1 A-lo ----
    STAGE8(gA, 0,     0, 0, 0, 0); STAGE8(gA, 0,     0, 1, 0, 0);
    STAGE8(gA, 0,     1, 0, 0, 0); STAGE8(gA, 0,     1, 1, 0, 0);
    STAGE8(gB, 16384, 0, 0, 0, 0); STAGE8(gB, 16384, 0, 1, 0, 0);
    STAGE8(gB, 16384, 1, 0, 0, 0); STAGE8(gB, 16384, 1, 1, 0, 0);
    STAGE8(gA, 0,     0, 0, 1, 1); STAGE8(gA, 0,     0, 1, 1, 1);
    asm volatile("s_waitcnt vmcnt(2)" ::: "memory");
    __builtin_amdgcn_s_barrier();

#define ARD(MI0)                                                                \
    a0 = *(const bf16x8*)(sAc + aoff + (MI0) * 1024 + fsw0);                    \
    a1 = *(const bf16x8*)(sAc + aoff + (MI0) * 1024 + fsw1);                    \
    a2 = *(const bf16x8*)(sAc + aoff + ((MI0) + 1) * 1024 + fsw0);              \
    a3 = *(const bf16x8*)(sAc + aoff + ((MI0) + 1) * 1024 + fsw1);

#define MFQ(MI0)                                                                \
    __builtin_amdgcn_s_setprio(1);                                              \
    _Pragma("unroll")                                                           \
    for (int nj = 0; nj < 4; ++nj) {                                            \
        acc[MI0][nj]       = mfma32k(a0, bf[nj][0], acc[MI0][nj]);              \
        acc[MI0][nj]       = mfma32k(a1, bf[nj][1], acc[MI0][nj]);              \
        acc[(MI0) + 1][nj] = mfma32k(a2, bf[nj][0], acc[(MI0) + 1][nj]);        \
        acc[(MI0) + 1][nj] = mfma32k(a3, bf[nj][1], acc[(MI0) + 1][nj]);        \
    }                                                                           \
    __builtin_amdgcn_s_setprio(0);

    for (int T = 0; T < 16; ++T) {
        const int cur = T & 1, nxt = cur ^ 1;
        const short* sAc = lds + cur * 32768;
        const short* sBc = sAc + 16384;
        bf16x8 bf[4][2];
#pragma unroll
        for (int nj = 0; nj < 4; ++nj) {
            bf[nj][0] = *(const bf16x8*)(sBc + boff + nj * 1024 + fsw0);
            bf[nj][1] = *(const bf16x8*)(sBc + boff + nj * 1024 + fsw1);
        }
        bf16x8 a0, a1, a2, a3;
        ARD(0)
        if (T < 15) { STAGE8(gA, 0, 1, 0, T + 1, nxt); STAGE8(gA, 0, 1, 1, T + 1, nxt); }
        __builtin_amdgcn_s_barrier();
        MFQ(0)
        __builtin_amdgcn_s_barrier();
        ARD(2)
        if (T < 15) { STAGE8(gB, 16384, 0, 0, T + 1, nxt); STAGE8(gB, 16384, 0, 1, T + 1, nxt); }
        __builtin_amdgcn_s_barrier();
        MFQ(2)
        __builtin_amdgcn_s_barrier();
        ARD(4)
        if (T < 15) { STAGE8(gB, 16384, 1, 0, T + 1, nxt); STAGE8(gB, 16384, 1, 1, T + 1, nxt); }
        __builtin_amdgcn_s_barrier();
        MFQ(4)
        __builtin_amdgcn_s_barrier();
        ARD(6)
        __builtin_amdgcn_s_barrier();
        MFQ(6)
        __builtin_amdgcn_s_barrier();
        if (T < 14) {
            STAGE8(gA, 0, 0, 0, T + 2, cur); STAGE8(gA, 0, 0, 1, T + 2, cur);
            asm volatile("s_waitcnt vmcnt(2)" ::: "memory");
            __builtin_amdgcn_s_barrier();
        } else if (T == 14) {
            asm volatile("s_waitcnt vmcnt(0)" ::: "memory");
            __builtin_amdgcn_s_barrier();
        }
    }
#undef ARD
#undef MFQ
#undef STAGE8

    // ---- epilogue A (no perm) ----
#pragma unroll
    for (int mi = 0; mi < 8; ++mi)
#pragma unroll
        for (int nj = 0; nj < 4; ++nj) {
            int row = bm * 256 + wm * 128 + mi * 16 + quad * 4;
            int col = bn * 256 + wn * 64 + nj * 16 + lane16;
#pragma unroll
            for (int r = 0; r < 4; ++r)
                C0[(size_t)(row + r) * 2048 + col] = f2bf(acc[mi][nj][r]);
        }

    // ---- phase B: VT 256x128 half-tile (4 x 64 = 256 of them) ----
    // R13 mapping: XCD x owns {all 4 vbm} x {vbn in [x*8, x*8+8)}
    const int vbm = ib >> 3, vbn = xcd * 8 + (ib & 7);
    const short* hA = A1 + (size_t)(vbm * 256 + grow) * 1024 + lsl;
    const short* hB = B1 + (size_t)(vbn * 128 + grow) * 1024 + lsl;
    f32x4 accB[4][4] = {};
    gemm_pipe_256x128(lds, hA, hB, wv, lane16, fsw0, fsw1, accB);

    const int wm2 = wv & 3, wn2 = wv >> 2;       // square wave grid (R12)
    const int sEven = (lane16 >> 2) * 8 + (lane16 & 3);   // kv-perm within 32-col blocks
#pragma unroll
    for (int mi = 0; mi < 4; ++mi)
#pragma unroll
        for (int nj = 0; nj < 4; ++nj) {
            int row = vbm * 256 + wm2 * 64 + mi * 16 + quad * 4;
            int col = vbn * 128 + wn2 * 64 + nj * 16 + lane16;
            col = (col & ~31) | (sEven + (nj & 1) * 4);
#pragma unroll
            for (int r = 0; r < 4; ++r)
                C1[(size_t)(row + r) * 8192 + col] = f2bf(accB[mi][nj][r]);
        }
}

// ---------- output projection GEMM: out[8192][1024] f32 = CTX @ Wo^T + bo ----------
// 256x128 tiles; grid 256 = one round. R13 rectangular XCD mapping (4bm x 8bn).
__global__ __launch_bounds__(512, 2)
void gemm_out(const short* __restrict__ A, const short* __restrict__ Bm,
              float* __restrict__ C, const float* __restrict__ bias) {
    __shared__ __align__(16) short lds[65536];
    const int t = threadIdx.x, l = t & 63, wv = t >> 6;
    const int lane16 = l & 15, quad = l >> 4;

    int bid = blockIdx.x;
    const int xcd = bid & 7, ib = bid >> 3;
    const int bm = xcd * 4 + (ib & 3), bn = ib >> 2;   // 32 x 8 tiles of 256x128

    const int grow = t >> 3;
    const int lsl  = ((t & 7) ^ ((t >> 3) & 7)) * 8;
    const short* hA = A  + (size_t)(bm * 256 + grow) * 1024 + lsl;
    const short* hB = Bm + (size_t)(bn * 128 + grow) * 1024 + lsl;

    const int fsw0 = ((quad)     ^ (lane16 & 7)) * 8;
    const int fsw1 = ((quad + 4) ^ (lane16 & 7)) * 8;

    f32x4 acc[4][4] = {};
    gemm_pipe_256x128(lds, hA, hB, wv, lane16, fsw0, fsw1, acc);

    const int wm2 = wv & 3, wn2 = wv >> 2;
#pragma unroll
    for (int mi = 0; mi < 4; ++mi)
#pragma unroll
        for (int nj = 0; nj < 4; ++nj) {
            int row = bm * 256 + wm2 * 64 + mi * 16 + quad * 4;
            int col = bn * 128 + wn2 * 64 + nj * 16 + lane16;
            float bv = bias[col];
#pragma unroll
            for (int r = 0; r < 4; ++r)
                C[(size_t)(row + r) * 1024 + col] = acc[mi][nj][r] + bv;
        }
}

// ---------- flash attention ----------
// QK[M][2048] bf16 (Q pre-scaled by CL2 | K), VT[1024][8192] bf16 (V^T, kv-permuted
// within 32-blocks), CTX[M][1024] bf16.
// S^T = K Q^T (P^T C-layout == A-frag layout), softmax without online max
// (scores provably bounded), P packed in-register via v_perm, PV via K=32 MFMA.
// Softmax denominator accumulated on the MATRIX pipe: lacc = mfma(P, ones, lacc).
//
// R13: diagnostic split reverted (single 1024-block dispatch). Body frozen at
// the m214 ~900 TF plain-HIP plateau (R5 swizzle + R7 2-deep pipeline kept).
__global__ __launch_bounds__(256, 4)
void attn_kernel(const short* __restrict__ QK, const short* __restrict__ VT,
                 short* __restrict__ CTX) {
    __shared__ __align__(16) short sK[8192];
    __shared__ __align__(16) short sV[8192];
    const int t = threadIdx.x, w = t >> 6, l = t & 63;
    const int lane16 = l & 15, quad = l >> 4;
    const int bh = blockIdx.x, qt = blockIdx.y;
    const int b = bh >> 4, h = bh & 15;

    const int qx8 = (quad ^ ((lane16 >> 1) & 3)) * 8;

    const short* Qb = QK + ((size_t)(b * 2048 + qt * 128)) * 2048 + h * 64;
    const short* Vb = VT + ((size_t)(h * 64)) * 8192 + (size_t)b * 2048;
    const int ldsOff = (w * 64) * 8;

    int off_kq[4], off_v[4];
#pragma unroll
    for (int p = 0; p < 4; ++p) {
        int c = p * 256 + t;
        int sw = ((c & 3) ^ ((c >> 3) & 3)) * 8;
        off_kq[p] = ((c >> 2) & 127) * 2048 + (c >> 9) * 32 + sw;
        off_v[p]  = ((c >> 2) & 63) * 8192 + (c >> 8) * 32 + sw;
    }

#pragma unroll
    for (int p = 0; p < 4; ++p)
        GLDS16(Qb + off_kq[p], sK + p * 2048 + ldsOff);
    __syncthreads();
    bf16x8 qf[2][2];
#pragma unroll
    for (int mt = 0; mt < 2; ++mt)
#pragma unroll
        for (int ks = 0; ks < 2; ++ks)
            qf[mt][ks] = *(const bf16x8*)(sK + ks * 4096 + (w * 32 + mt * 16 + lane16) * 32 + qx8);
    __syncthreads();

    const short one = (short)0x3F80;
    const bf16x8 ONE8 = {one, one, one, one, one, one, one, one};
    f32x4 lacc[2] = {};
    f32x4 o[2][4] = {};

    const short* kptr = QK + ((size_t)(b * 2048)) * 2048 + 1024 + h * 64;
    const short* vptr = Vb;

    auto QKB = [&](int a, f32x4 (&sc)[2][2]) {
        __builtin_amdgcn_s_setprio(1);
#pragma unroll
        for (int sub = 0; sub < 2; ++sub) {
            int nt = a * 2 + sub;
            bf16x8 kf0 = *(const bf16x8*)(sK + (nt * 16 + lane16) * 32 + qx8);
            bf16x8 kf1 = *(const bf16x8*)(sK + 4096 + (nt * 16 + lane16) * 32 + qx8);
#pragma unroll
            for (int mt = 0; mt < 2; ++mt) {
                f32x4 z = {};
                z = mfma32k(kf0, qf[mt][0], z);
                z = mfma32k(kf1, qf[mt][1], z);
                sc[mt][sub] = z;
            }
        }
        __builtin_amdgcn_s_setprio(0);
    };
    auto PVB = [&](int a, f32x4 (&sc)[2][2]) {
        bf16x8 pf[2];
#pragma unroll
        for (int mt = 0; mt < 2; ++mt) {
            union { int i[4]; bf16x8 v; } u;
#pragma unroll
            for (int sub = 0; sub < 2; ++sub) {
                f32x4 e;
#pragma unroll
                for (int r = 0; r < 4; ++r)
                    e[r] = __builtin_amdgcn_exp2f(sc[mt][sub][r]);
                u.i[sub * 2]     = pack2(e[0], e[1]);
                u.i[sub * 2 + 1] = pack2(e[2], e[3]);
            }
            pf[mt] = u.v;
        }
        __builtin_amdgcn_s_setprio(1);
#pragma unroll
        for (int mt = 0; mt < 2; ++mt)
            lacc[mt] = mfma32k(pf[mt], ONE8, lacc[mt]);
#pragma unroll
        for (int dt = 0; dt < 4; ++dt) {
            bf16x8 vf = *(const bf16x8*)(sV + a * 2048 + (dt * 16 + lane16) * 32 + qx8);
#pragma unroll
            for (int mt = 0; mt < 2; ++mt)
                o[mt][dt] = mfma32k(pf[mt], vf, o[mt][dt]);
        }
        __builtin_amdgcn_s_setprio(0);
    };

    for (int kt = 0; kt < 16; ++kt) {
#pragma unroll
        for (int p = 0; p < 4; ++p)
            GLDS16(kptr + off_kq[p], sK + p * 2048 + ldsOff);
#pragma unroll
        for (int p = 0; p < 4; ++p)
            GLDS16(vptr + off_v[p], sV + p * 2048 + ldsOff);
        kptr += (size_t)128 * 2048;
        vptr += 128;
        __syncthreads();

        f32x4 scA[2][2], scB[2][2];
        QKB(0, scA);
        QKB(1, scB);  PVB(0, scA);
        QKB(2, scA);  PVB(1, scB);
        QKB(3, scB);  PVB(2, scA);
                      PVB(3, scB);
        __syncthreads();
    }

#pragma unroll
    for (int mt = 0; mt < 2; ++mt)
#pragma unroll
        for (int r = 0; r < 4; ++r) {
            float inv = 1.0f / lacc[mt][r];
            int row = b * 2048 + qt * 128 + w * 32 + mt * 16 + quad * 4 + r;
#pragma unroll
            for (int dt = 0; dt < 4; ++dt)
                CTX[(size_t)row * 1024 + h * 64 + dt * 16 + lane16] = f2bf(o[mt][dt][r] * inv);
        }
}

// ---------- launch ----------
extern "C" void kernel_launch(void* const* d_in, const int* in_sizes, int n_in,
                              void* d_out, int out_size, void* d_ws, size_t ws_size,
                              hipStream_t stream) {
    const float* X  = (const float*)d_in[0];
    const float* Wq = (const float*)d_in[1];
    const float* Wk = (const float*)d_in[2];
    const float* Wv = (const float*)d_in[3];
    const float* Wo = (const float*)d_in[4];
    const float* bo = (const float*)d_in[5];
    float* out = (float*)d_out;

    char* ws = (char*)d_ws;
    constexpr size_t OFF_XB  = 0;                                   // 16 MB
    constexpr size_t OFF_WQK = OFF_XB  + (size_t)Mrows * Ee * 2;    //  4 MB
    constexpr size_t OFF_WV  = OFF_WQK + (size_t)2 * Ee * Ee * 2;   //  2 MB
    constexpr size_t OFF_WO  = OFF_WV  + (size_t)Ee * Ee * 2;       //  2 MB
    constexpr size_t OFF_QK  = OFF_WO  + (size_t)Ee * Ee * 2;       // 32 MB
    constexpr size_t OFF_VT  = OFF_QK  + (size_t)Mrows * 2048 * 2;  // 16 MB
    constexpr size_t OFF_CTX = OFF_VT  + (size_t)Ee * Mrows * 2;    // 16 MB
    short* Xb   = (short*)(ws + OFF_XB);
    short* Wqk  = (short*)(ws + OFF_WQK);
    short* Wvb  = (short*)(ws + OFF_WV);
    short* Wob  = (short*)(ws + OFF_WO);
    short* QKb  = (short*)(ws + OFF_QK);
    short* VTb  = (short*)(ws + OFF_VT);
    short* CTX  = (short*)(ws + OFF_CTX);

    // all converts in one launch (X, Wq*CL2 | Wk, Wv, Wo)
    cvt_all<<<12288, 256, 0, stream>>>(X, Wq, Wk, Wv, Wo, Xb, Wqk, Wvb, Wob);

    // persistent 256-block fused GEMM: QK 256^2 tile + VT 256x128 half-tile each
    gemm_fused<<<256, 512, 0, stream>>>(Xb, Wqk, QKb, Wvb, Xb, VTb);

    // attention: CTX [8192][1024] bf16 (single dispatch)
    attn_kernel<<<dim3(Bb * Hh, Ss / 128), 256, 0, stream>>>(QKb, VTb, CTX);

    // output projection + bias: f32 out (256 blocks = one round)
    gemm_out<<<256, 512, 0, stream>>>(CTX, Wob, out, bo);
}